// Round 7
// baseline (207.846 us; speedup 1.0000x reference)
//
#include <hip/hip_runtime.h>
#include <hip/hip_bf16.h>
#include <stdint.h>

typedef unsigned short u16;
typedef __attribute__((ext_vector_type(8))) short short8;
typedef __attribute__((ext_vector_type(4))) float f32x4;

#define BB 4
#define NN 8192
#define SS 2048
#define MTOT 32768
#define CSKIP 256
#define CLO 512
#define CIN 768
#define COUT 256

__device__ __forceinline__ u16 f2bf(float f) {
  unsigned u = __float_as_uint(f);
  u += 0x7fffu + ((u >> 16) & 1u);
  return (u16)(u >> 16);
}

__device__ __forceinline__ void gl_lds16(const void* g, void* l) {
  __builtin_amdgcn_global_load_lds(
      (const __attribute__((address_space(1))) void*)g,
      (__attribute__((address_space(3))) void*)l, 16, 0, 0);
}

// ---------------------------------------------------------------------------
// K0: weights -> bf16 transposed [n][k]
// ---------------------------------------------------------------------------
__global__ __launch_bounds__(256) void wconv_kernel(const float* __restrict__ W1,
                                                    const float* __restrict__ W2,
                                                    u16* __restrict__ W1T,
                                                    u16* __restrict__ W2T) {
  int i = blockIdx.x * 256 + threadIdx.x;
  if (i < CIN * COUT) {
    int n = i / CIN, k = i - n * CIN;
    W1T[i] = f2bf(W1[(size_t)k * COUT + n]);
  } else if (i < CIN * COUT + COUT * COUT) {
    int j = i - CIN * COUT;
    int n = j >> 8, k = j & 255;
    W2T[j] = f2bf(W2[(size_t)k * COUT + n]);
  }
}

// ---------------------------------------------------------------------------
// K1: KNN (K=3), diff-form fp32 distances (expansion form flips near-ties —
// R3 failure). lane = query, wave = candidate-partition; LDS reads are
// wave-uniform (broadcast, conflict-free).
// ---------------------------------------------------------------------------
__global__ __launch_bounds__(512) void knn_kernel(
    const float* __restrict__ xyz_hi, const float* __restrict__ xyz_lo,
    float* __restrict__ wq_g, int* __restrict__ iq_g) {
  __shared__ float4 sxyz[SS];          // 32 KB
  __shared__ float md[8][64][3];
  __shared__ int   mi[8][64][3];

  int tid = threadIdx.x;
  int blk = blockIdx.x;
  int b = blk >> 7;                    // 128 blocks per batch
  const float* xl = xyz_lo + (size_t)b * SS * 3;
  for (int j = tid; j < SS; j += 512)
    sxyz[j] = make_float4(xl[j * 3 + 0], xl[j * 3 + 1], xl[j * 3 + 2], 0.f);
  __syncthreads();

  int wave = tid >> 6, lane = tid & 63;
  int qm = blk * 64 + lane;
  float qx = xyz_hi[(size_t)qm * 3 + 0];
  float qy = xyz_hi[(size_t)qm * 3 + 1];
  float qz = xyz_hi[(size_t)qm * 3 + 2];

  float b0 = 1e30f, b1 = 1e30f, b2 = 1e30f;
  int i0 = -1, i1 = -1, i2 = -1;
  int j0 = wave * 256;
#pragma unroll 4
  for (int jj = 0; jj < 256; ++jj) {
    int j = j0 + jj;
    float4 p = sxyz[j];
    float dx = p.x - qx, dy = p.y - qy, dz = p.z - qz;
    float d = fmaf(dx, dx, fmaf(dy, dy, dz * dz));
    bool c = d < b2;
    b2 = c ? d : b2; i2 = c ? j : i2;
    bool s = b2 < b1;
    float tb = b1; b1 = s ? b2 : b1; b2 = s ? tb : b2;
    int ti = i1;   i1 = s ? i2 : i1; i2 = s ? ti : i2;
    bool v = b1 < b0;
    float ub = b0; b0 = v ? b1 : b0; b1 = v ? ub : b1;
    int ui = i0;   i0 = v ? i1 : i0; i1 = v ? ui : i1;
  }
  md[wave][lane][0] = b0; mi[wave][lane][0] = i0;
  md[wave][lane][1] = b1; mi[wave][lane][1] = i1;
  md[wave][lane][2] = b2; mi[wave][lane][2] = i2;
  __syncthreads();

  if (tid < 64) {
    int q = tid;
    float fb0 = 1e30f, fb1 = 1e30f, fb2 = 1e30f;
    int fi0 = -1, fi1 = -1, fi2 = -1;
    for (int p = 0; p < 8; ++p)
#pragma unroll
      for (int s = 0; s < 3; ++s) {
        float d = md[p][q][s]; int ix = mi[p][q][s];
        if (d < fb2 || (d == fb2 && ix < fi2)) {
          fb2 = d; fi2 = ix;
          if (fb2 < fb1 || (fb2 == fb1 && fi2 < fi1)) {
            float t = fb1; fb1 = fb2; fb2 = t; int ti = fi1; fi1 = fi2; fi2 = ti;
          }
          if (fb1 < fb0 || (fb1 == fb0 && fi1 < fi0)) {
            float t = fb0; fb0 = fb1; fb1 = t; int ti = fi0; fi0 = fi1; fi1 = ti;
          }
        }
      }
    int qm2 = blk * 64 + q;
    float d0 = sqrtf(fb0), d1 = sqrtf(fb1), d2 = sqrtf(fb2);
    float inv0 = 1.0f / (d0 + 1e-8f);
    float inv1 = 1.0f / (d1 + 1e-8f);
    float inv2 = 1.0f / (d2 + 1e-8f);
    float s = inv0 + inv1 + inv2;
    wq_g[(size_t)qm2 * 3 + 0] = inv0 / s;
    wq_g[(size_t)qm2 * 3 + 1] = inv1 / s;
    wq_g[(size_t)qm2 * 3 + 2] = inv2 / s;
    iq_g[(size_t)qm2 * 3 + 0] = fi0;
    iq_g[(size_t)qm2 * 3 + 1] = fi1;
    iq_g[(size_t)qm2 * 3 + 2] = fi2;
  }
}

// ---------------------------------------------------------------------------
// K2: fused GEMM1. Tile 32x256, 256 thr (4 waves across N), BK=32, grid 1024
// -> 4 blocks/CU: four independent barrier groups per CU hide the scattered
// A-gather latency (R4/R6's 1.5-2 blocks/CU left it exposed). As rows padded
// to 40 u16 (2-way max, free); Bs xor-swizzled 16B slots (gl_lds needs
// lane-contiguous dst, padding illegal).
// ---------------------------------------------------------------------------
__global__ __launch_bounds__(256, 4) void gemm1_fused_kernel(
    const float* __restrict__ feat_skip, const float* __restrict__ feat_lo,
    const float* __restrict__ wq_g, const int* __restrict__ iq_g,
    const u16* __restrict__ W1T, const float* __restrict__ b1,
    u16* __restrict__ H) {
  __shared__ u16 As[32 * 40];    // 2.5 KB
  __shared__ u16 Bs[256 * 32];   // 16 KB (1024 16B slots, swizzled)
  int tid = threadIdx.x;
  int m0 = blockIdx.x << 5;
  int b = blockIdx.x >> 8;       // 256 blocks per batch
  int w = tid >> 6, lane = tid & 63;
  int quad = lane >> 4, l16 = lane & 15;

  // staging: row = tid>>3 (0..31), 4-channel slice s4 = (tid&7)*4
  int srow = tid >> 3, s4 = (tid & 7) << 2;
  float w0 = wq_g[(size_t)(m0 + srow) * 3 + 0];
  float w1 = wq_g[(size_t)(m0 + srow) * 3 + 1];
  float w2 = wq_g[(size_t)(m0 + srow) * 3 + 2];
  int i0 = iq_g[(size_t)(m0 + srow) * 3 + 0];
  int i1 = iq_g[(size_t)(m0 + srow) * 3 + 1];
  int i2 = iq_g[(size_t)(m0 + srow) * 3 + 2];
  const float* fl0 = feat_lo + ((size_t)b * SS + i0) * CLO + s4;
  const float* fl1 = feat_lo + ((size_t)b * SS + i1) * CLO + s4;
  const float* fl2 = feat_lo + ((size_t)b * SS + i2) * CLO + s4;
  const float* fsk = feat_skip + (size_t)(m0 + srow) * CSKIP + s4;
  u16* As_dst = As + srow * 40 + s4;

  f32x4 zero = {0.f, 0.f, 0.f, 0.f};
  f32x4 acc[2][4];
#pragma unroll
  for (int tm = 0; tm < 2; ++tm)
#pragma unroll
    for (int tn = 0; tn < 4; ++tn) acc[tm][tn] = zero;

  for (int kc = 0; kc < 24; ++kc) {
    __syncthreads();
    // B stage: W1T 256x32 chunk -> 1024 swizzled 16B slots
#pragma unroll
    for (int r = 0; r < 4; ++r) {
      int u = tid + r * 256;
      int nrow = u >> 2, c = u & 3;
      int cg = c ^ (nrow & 3);
      gl_lds16(W1T + (size_t)nrow * CIN + kc * 32 + cg * 8, (char*)Bs + u * 16);
    }
    // A stage: 4 channels -> bf16 -> 8B ds_write
    float4 av;
    if (kc < 8) {
      av = *(const float4*)(fsk + kc * 32);
    } else {
      int c0 = (kc - 8) * 32;
      float4 a = *(const float4*)(fl0 + c0);
      float4 d = *(const float4*)(fl1 + c0);
      float4 e = *(const float4*)(fl2 + c0);
      av.x = fmaf(w0, a.x, fmaf(w1, d.x, w2 * e.x));
      av.y = fmaf(w0, a.y, fmaf(w1, d.y, w2 * e.y));
      av.z = fmaf(w0, a.z, fmaf(w1, d.z, w2 * e.z));
      av.w = fmaf(w0, a.w, fmaf(w1, d.w, w2 * e.w));
    }
    union { __hip_bfloat162 h2[2]; uint2 u2; } pk;
    pk.h2[0] = __float22bfloat162_rn(make_float2(av.x, av.y));
    pk.h2[1] = __float22bfloat162_rn(make_float2(av.z, av.w));
    *(uint2*)As_dst = pk.u2;
    __syncthreads();

    short8 af[2], bf[4];
#pragma unroll
    for (int t = 0; t < 2; ++t)
      af[t] = *(const short8*)(As + (t * 16 + l16) * 40 + quad * 8);
#pragma unroll
    for (int t = 0; t < 4; ++t) {
      int rr = w * 64 + t * 16 + l16;
      bf[t] = *(const short8*)(Bs + (rr * 4 + (quad ^ (rr & 3))) * 8);
    }
#pragma unroll
    for (int tm = 0; tm < 2; ++tm)
#pragma unroll
      for (int tn = 0; tn < 4; ++tn)
        acc[tm][tn] = __builtin_amdgcn_mfma_f32_16x16x32_bf16(af[tm], bf[tn], acc[tm][tn], 0, 0, 0);
  }

  float bias[4];
#pragma unroll
  for (int tn = 0; tn < 4; ++tn) bias[tn] = b1[w * 64 + tn * 16 + l16];
#pragma unroll
  for (int tm = 0; tm < 2; ++tm)
#pragma unroll
    for (int tn = 0; tn < 4; ++tn) {
      int col = w * 64 + tn * 16 + l16;
#pragma unroll
      for (int r = 0; r < 4; ++r) {
        int row = m0 + tm * 16 + quad * 4 + r;
        float v = acc[tm][tn][r] + bias[tn];
        v = v > 0.f ? v : 0.f;
        H[(size_t)row * COUT + col] = f2bf(v);
      }
    }
}

// ---------------------------------------------------------------------------
// K3: GEMM2 + bias + LayerNorm. Tile 32x256, 256 thr, BK=32, grid 1024
// (4 blocks/CU). A and B staged via xor-swizzled gl_lds.
// ---------------------------------------------------------------------------
__global__ __launch_bounds__(256, 4) void gemm2_ln_kernel(const u16* __restrict__ H,
                                                          const u16* __restrict__ Bt,
                                                          const float* __restrict__ b2,
                                                          const float* __restrict__ gamma,
                                                          const float* __restrict__ beta,
                                                          float* __restrict__ out) {
  __shared__ u16 As[32 * 32];    // 2 KB (128 slots, swizzled)
  __shared__ u16 Bs[256 * 32];   // 16 KB
  __shared__ float red[4][32][2];
  __shared__ float stats[32][2];
  int tid = threadIdx.x;
  int m0 = blockIdx.x << 5;
  int w = tid >> 6, lane = tid & 63;
  int quad = lane >> 4, l16 = lane & 15;

  f32x4 zero = {0.f, 0.f, 0.f, 0.f};
  f32x4 acc[2][4];
#pragma unroll
  for (int tm = 0; tm < 2; ++tm)
#pragma unroll
    for (int tn = 0; tn < 4; ++tn) acc[tm][tn] = zero;

  for (int kc = 0; kc < 8; ++kc) {
    __syncthreads();
    if (tid < 128) {               // waves 0,1: A chunk (32 rows x 64 B)
      int row = tid >> 2, c = tid & 3;
      int cg = c ^ (row & 3);
      gl_lds16(H + (size_t)(m0 + row) * COUT + kc * 32 + cg * 8, (char*)As + tid * 16);
    }
#pragma unroll
    for (int r = 0; r < 4; ++r) {
      int u = tid + r * 256;
      int nrow = u >> 2, c = u & 3;
      int cg = c ^ (nrow & 3);
      gl_lds16(Bt + (size_t)nrow * COUT + kc * 32 + cg * 8, (char*)Bs + u * 16);
    }
    __syncthreads();

    short8 af[2], bf[4];
#pragma unroll
    for (int t = 0; t < 2; ++t) {
      int ra = t * 16 + l16;
      af[t] = *(const short8*)(As + (ra * 4 + (quad ^ (ra & 3))) * 8);
    }
#pragma unroll
    for (int t = 0; t < 4; ++t) {
      int rr = w * 64 + t * 16 + l16;
      bf[t] = *(const short8*)(Bs + (rr * 4 + (quad ^ (rr & 3))) * 8);
    }
#pragma unroll
    for (int tm = 0; tm < 2; ++tm)
#pragma unroll
      for (int tn = 0; tn < 4; ++tn)
        acc[tm][tn] = __builtin_amdgcn_mfma_f32_16x16x32_bf16(af[tm], bf[tn], acc[tm][tn], 0, 0, 0);
  }

  float bias[4], g[4], be[4];
#pragma unroll
  for (int tn = 0; tn < 4; ++tn) {
    int col = w * 64 + tn * 16 + l16;
    bias[tn] = b2[col]; g[tn] = gamma[col]; be[tn] = beta[col];
  }
#pragma unroll
  for (int tm = 0; tm < 2; ++tm)
#pragma unroll
    for (int r = 0; r < 4; ++r) {
      float s = 0.f, sq = 0.f;
#pragma unroll
      for (int tn = 0; tn < 4; ++tn) {
        float v = acc[tm][tn][r] + bias[tn];
        acc[tm][tn][r] = v;
        s += v; sq += v * v;
      }
#pragma unroll
      for (int msk = 1; msk < 16; msk <<= 1) {
        s += __shfl_xor(s, msk);
        sq += __shfl_xor(sq, msk);
      }
      if (l16 == 0) {
        int rl = tm * 16 + quad * 4 + r;
        red[w][rl][0] = s;
        red[w][rl][1] = sq;
      }
    }
  __syncthreads();
  if (tid < 32) {
    float s = red[0][tid][0] + red[1][tid][0] + red[2][tid][0] + red[3][tid][0];
    float sq = red[0][tid][1] + red[1][tid][1] + red[2][tid][1] + red[3][tid][1];
    float mu = s * (1.f / 256.f);
    float var = sq * (1.f / 256.f) - mu * mu;
    stats[tid][0] = mu;
    stats[tid][1] = rsqrtf(var + 1e-5f);
  }
  __syncthreads();
#pragma unroll
  for (int tm = 0; tm < 2; ++tm)
#pragma unroll
    for (int r = 0; r < 4; ++r) {
      int rl = tm * 16 + quad * 4 + r;
      float mu = stats[rl][0], rstd = stats[rl][1];
#pragma unroll
      for (int tn = 0; tn < 4; ++tn) {
        int col = w * 64 + tn * 16 + l16;
        out[(size_t)(m0 + rl) * COUT + col] = (acc[tm][tn][r] - mu) * rstd * g[tn] + be[tn];
      }
    }
}

// ---------------------------------------------------------------------------
extern "C" void kernel_launch(void* const* d_in, const int* in_sizes, int n_in,
                              void* d_out, int out_size, void* d_ws, size_t ws_size,
                              hipStream_t stream) {
  const float* xyz_hi    = (const float*)d_in[0];
  const float* xyz_lo    = (const float*)d_in[1];
  const float* feat_skip = (const float*)d_in[2];
  const float* feat_lo   = (const float*)d_in[3];
  const float* W1        = (const float*)d_in[4];
  const float* b1        = (const float*)d_in[5];
  const float* W2        = (const float*)d_in[6];
  const float* b2        = (const float*)d_in[7];
  const float* gamma     = (const float*)d_in[8];
  const float* beta      = (const float*)d_in[9];
  float* out = (float*)d_out;

  char* ws = (char*)d_ws;
  u16*   H    = (u16*)ws;                                  // 16777216
  u16*   W1T  = (u16*)(ws + 16777216);                     // 393216
  u16*   W2T  = (u16*)(ws + 16777216 + 393216);            // 131072
  float* wq_g = (float*)(ws + 16777216 + 393216 + 131072); // 393216
  int*   iq_g = (int*)(ws + 16777216 + 393216 + 131072 + 393216);

  wconv_kernel<<<1024, 256, 0, stream>>>(W1, W2, W1T, W2T);
  knn_kernel<<<MTOT / 64, 512, 0, stream>>>(xyz_hi, xyz_lo, wq_g, iq_g);
  gemm1_fused_kernel<<<MTOT / 32, 256, 0, stream>>>(feat_skip, feat_lo, wq_g, iq_g, W1T, b1, H);
  gemm2_ln_kernel<<<MTOT / 32, 256, 0, stream>>>(H, W2T, b2, gamma, beta, out);
}

// Round 8
// 190.405 us; speedup vs baseline: 1.0916x; 1.0916x over previous
//
#include <hip/hip_runtime.h>
#include <hip/hip_bf16.h>
#include <stdint.h>

typedef unsigned short u16;
typedef __attribute__((ext_vector_type(8))) short short8;
typedef __attribute__((ext_vector_type(4))) float f32x4;

#define BB 4
#define NN 8192
#define SS 2048
#define MTOT 32768
#define CSKIP 256
#define CLO 512
#define CIN 768
#define COUT 256

__device__ __forceinline__ u16 f2bf(float f) {
  unsigned u = __float_as_uint(f);
  u += 0x7fffu + ((u >> 16) & 1u);
  return (u16)(u >> 16);
}

__device__ __forceinline__ void gl_lds16(const void* g, void* l) {
  __builtin_amdgcn_global_load_lds(
      (const __attribute__((address_space(1))) void*)g,
      (__attribute__((address_space(3))) void*)l, 16, 0, 0);
}

// ---------------------------------------------------------------------------
// K0: weights -> bf16 transposed.  W1 split: W1a = W1[0:256,:] (skip part),
// W1b = W1[256:768,:] (interp part).  W1aT[n][k<256], W1bT[n][k<512], W2T.
// ---------------------------------------------------------------------------
__global__ __launch_bounds__(256) void wconv_kernel(const float* __restrict__ W1,
                                                    const float* __restrict__ W2,
                                                    u16* __restrict__ W1aT,
                                                    u16* __restrict__ W1bT,
                                                    u16* __restrict__ W2T) {
  int i = blockIdx.x * 256 + threadIdx.x;
  if (i < 65536) {                       // W1aT: n=i>>8, k=i&255
    int n = i >> 8, k = i & 255;
    W1aT[i] = f2bf(W1[(size_t)k * COUT + n]);
  } else if (i < 65536 + 131072) {       // W1bT: n=j>>9, k=j&511
    int j = i - 65536;
    int n = j >> 9, k = j & 511;
    W1bT[j] = f2bf(W1[(size_t)(256 + k) * COUT + n]);
  } else {                               // W2T
    int j = i - 65536 - 131072;
    int n = j >> 8, k = j & 255;
    W2T[j] = f2bf(W2[(size_t)k * COUT + n]);
  }
}

// ---------------------------------------------------------------------------
// K1: KNN (K=3), diff-form fp32 distances (expansion form flips near-ties —
// R3 failure). lane = query, wave = candidate-partition; LDS reads broadcast.
// ---------------------------------------------------------------------------
__global__ __launch_bounds__(512) void knn_kernel(
    const float* __restrict__ xyz_hi, const float* __restrict__ xyz_lo,
    float* __restrict__ wq_g, int* __restrict__ iq_g) {
  __shared__ float4 sxyz[SS];
  __shared__ float md[8][64][3];
  __shared__ int   mi[8][64][3];

  int tid = threadIdx.x;
  int blk = blockIdx.x;
  int b = blk >> 7;
  const float* xl = xyz_lo + (size_t)b * SS * 3;
  for (int j = tid; j < SS; j += 512)
    sxyz[j] = make_float4(xl[j * 3 + 0], xl[j * 3 + 1], xl[j * 3 + 2], 0.f);
  __syncthreads();

  int wave = tid >> 6, lane = tid & 63;
  int qm = blk * 64 + lane;
  float qx = xyz_hi[(size_t)qm * 3 + 0];
  float qy = xyz_hi[(size_t)qm * 3 + 1];
  float qz = xyz_hi[(size_t)qm * 3 + 2];

  float b0 = 1e30f, b1 = 1e30f, b2 = 1e30f;
  int i0 = -1, i1 = -1, i2 = -1;
  int j0 = wave * 256;
#pragma unroll 4
  for (int jj = 0; jj < 256; ++jj) {
    int j = j0 + jj;
    float4 p = sxyz[j];
    float dx = p.x - qx, dy = p.y - qy, dz = p.z - qz;
    float d = fmaf(dx, dx, fmaf(dy, dy, dz * dz));
    bool c = d < b2;
    b2 = c ? d : b2; i2 = c ? j : i2;
    bool s = b2 < b1;
    float tb = b1; b1 = s ? b2 : b1; b2 = s ? tb : b2;
    int ti = i1;   i1 = s ? i2 : i1; i2 = s ? ti : i2;
    bool v = b1 < b0;
    float ub = b0; b0 = v ? b1 : b0; b1 = v ? ub : b1;
    int ui = i0;   i0 = v ? i1 : i0; i1 = v ? ui : i1;
  }
  md[wave][lane][0] = b0; mi[wave][lane][0] = i0;
  md[wave][lane][1] = b1; mi[wave][lane][1] = i1;
  md[wave][lane][2] = b2; mi[wave][lane][2] = i2;
  __syncthreads();

  if (tid < 64) {
    int q = tid;
    float fb0 = 1e30f, fb1 = 1e30f, fb2 = 1e30f;
    int fi0 = -1, fi1 = -1, fi2 = -1;
    for (int p = 0; p < 8; ++p)
#pragma unroll
      for (int s = 0; s < 3; ++s) {
        float d = md[p][q][s]; int ix = mi[p][q][s];
        if (d < fb2 || (d == fb2 && ix < fi2)) {
          fb2 = d; fi2 = ix;
          if (fb2 < fb1 || (fb2 == fb1 && fi2 < fi1)) {
            float t = fb1; fb1 = fb2; fb2 = t; int ti = fi1; fi1 = fi2; fi2 = ti;
          }
          if (fb1 < fb0 || (fb1 == fb0 && fi1 < fi0)) {
            float t = fb0; fb0 = fb1; fb1 = t; int ti = fi0; fi0 = fi1; fi1 = ti;
          }
        }
      }
    int qm2 = blk * 64 + q;
    float d0 = sqrtf(fb0), d1 = sqrtf(fb1), d2 = sqrtf(fb2);
    float inv0 = 1.0f / (d0 + 1e-8f);
    float inv1 = 1.0f / (d1 + 1e-8f);
    float inv2 = 1.0f / (d2 + 1e-8f);
    float s = inv0 + inv1 + inv2;
    wq_g[(size_t)qm2 * 3 + 0] = inv0 / s;
    wq_g[(size_t)qm2 * 3 + 1] = inv1 / s;
    wq_g[(size_t)qm2 * 3 + 2] = inv2 / s;
    iq_g[(size_t)qm2 * 3 + 0] = fi0;
    iq_g[(size_t)qm2 * 3 + 1] = fi1;
    iq_g[(size_t)qm2 * 3 + 2] = fi2;
  }
}

// ---------------------------------------------------------------------------
// K2: ggemm — G = feat_lo @ W1b  (dense, M=8192, K=512, N=256, fp32 out).
// Tile 32x256, 256 thr, BK=32, grid 256.
// ---------------------------------------------------------------------------
__global__ __launch_bounds__(256, 4) void ggemm_kernel(
    const float* __restrict__ feat_lo, const u16* __restrict__ W1bT,
    float* __restrict__ G) {
  __shared__ u16 As[32 * 40];    // padded rows
  __shared__ u16 Bs[256 * 32];   // xor-swizzled 16B slots
  int tid = threadIdx.x;
  int m0 = blockIdx.x << 5;
  int w = tid >> 6, lane = tid & 63;
  int quad = lane >> 4, l16 = lane & 15;

  int srow = tid >> 3, s4 = (tid & 7) << 2;
  const float* arow = feat_lo + (size_t)(m0 + srow) * CLO + s4;
  u16* As_dst = As + srow * 40 + s4;

  f32x4 zero = {0.f, 0.f, 0.f, 0.f};
  f32x4 acc[2][4];
#pragma unroll
  for (int tm = 0; tm < 2; ++tm)
#pragma unroll
    for (int tn = 0; tn < 4; ++tn) acc[tm][tn] = zero;

  for (int kc = 0; kc < 16; ++kc) {
    __syncthreads();
#pragma unroll
    for (int r = 0; r < 4; ++r) {
      int u = tid + r * 256;
      int nrow = u >> 2, c = u & 3;
      int cg = c ^ (nrow & 3);
      gl_lds16(W1bT + (size_t)nrow * CLO + kc * 32 + cg * 8, (char*)Bs + u * 16);
    }
    float4 av = *(const float4*)(arow + kc * 32);
    union { __hip_bfloat162 h2[2]; uint2 u2; } pk;
    pk.h2[0] = __float22bfloat162_rn(make_float2(av.x, av.y));
    pk.h2[1] = __float22bfloat162_rn(make_float2(av.z, av.w));
    *(uint2*)As_dst = pk.u2;
    __syncthreads();

    short8 af[2], bf[4];
#pragma unroll
    for (int t = 0; t < 2; ++t)
      af[t] = *(const short8*)(As + (t * 16 + l16) * 40 + quad * 8);
#pragma unroll
    for (int t = 0; t < 4; ++t) {
      int rr = w * 64 + t * 16 + l16;
      bf[t] = *(const short8*)(Bs + (rr * 4 + (quad ^ (rr & 3))) * 8);
    }
#pragma unroll
    for (int tm = 0; tm < 2; ++tm)
#pragma unroll
      for (int tn = 0; tn < 4; ++tn)
        acc[tm][tn] = __builtin_amdgcn_mfma_f32_16x16x32_bf16(af[tm], bf[tn], acc[tm][tn], 0, 0, 0);
  }

#pragma unroll
  for (int tm = 0; tm < 2; ++tm)
#pragma unroll
    for (int tn = 0; tn < 4; ++tn) {
      int col = w * 64 + tn * 16 + l16;
#pragma unroll
      for (int r = 0; r < 4; ++r) {
        int row = m0 + tm * 16 + quad * 4 + r;
        G[(size_t)row * COUT + col] = acc[tm][tn][r];
      }
    }
}

// ---------------------------------------------------------------------------
// K3: gemm1' — H = relu(skip@W1a + b1 + sum_k wk*G[ik])  (bf16 out).
// Dense streaming A (feat_skip), K=256, tile 64x256, 256 thr, grid 512.
// IDW-gather moved to the epilogue: 3 fp32 reads/elem from L2-resident G.
// ---------------------------------------------------------------------------
__global__ __launch_bounds__(256, 2) void gemm1p_kernel(
    const float* __restrict__ feat_skip, const u16* __restrict__ W1aT,
    const float* __restrict__ b1, const float* __restrict__ G,
    const float* __restrict__ wq_g, const int* __restrict__ iq_g,
    u16* __restrict__ H) {
  __shared__ u16 As[64 * 40];    // 5 KB, padded rows
  __shared__ u16 Bs[256 * 32];   // 16 KB, xor-swizzled
  __shared__ float swq[192];
  __shared__ int   siq[192];
  int tid = threadIdx.x;
  int m0 = blockIdx.x << 6;
  int bS = (m0 >> 13) * SS;      // batch base row in G
  int w = tid >> 6, lane = tid & 63;
  int quad = lane >> 4, l16 = lane & 15;

  if (tid < 192) {
    swq[tid] = wq_g[(size_t)m0 * 3 + tid];
    siq[tid] = iq_g[(size_t)m0 * 3 + tid];
  }

  int srow = tid >> 2, sc8 = (tid & 3) << 3;
  const float* arow = feat_skip + (size_t)(m0 + srow) * CSKIP + sc8;
  u16* As_dst = As + srow * 40 + sc8;

  f32x4 zero = {0.f, 0.f, 0.f, 0.f};
  f32x4 acc[4][4];
#pragma unroll
  for (int tm = 0; tm < 4; ++tm)
#pragma unroll
    for (int tn = 0; tn < 4; ++tn) acc[tm][tn] = zero;

  for (int kc = 0; kc < 8; ++kc) {
    __syncthreads();
#pragma unroll
    for (int r = 0; r < 4; ++r) {
      int u = tid + r * 256;
      int nrow = u >> 2, c = u & 3;
      int cg = c ^ (nrow & 3);
      gl_lds16(W1aT + (size_t)nrow * CSKIP + kc * 32 + cg * 8, (char*)Bs + u * 16);
    }
    float4 x0 = *(const float4*)(arow + kc * 32);
    float4 x1 = *(const float4*)(arow + kc * 32 + 4);
    union { __hip_bfloat162 h2[4]; uint4 u4; } pk;
    pk.h2[0] = __float22bfloat162_rn(make_float2(x0.x, x0.y));
    pk.h2[1] = __float22bfloat162_rn(make_float2(x0.z, x0.w));
    pk.h2[2] = __float22bfloat162_rn(make_float2(x1.x, x1.y));
    pk.h2[3] = __float22bfloat162_rn(make_float2(x1.z, x1.w));
    *(uint4*)As_dst = pk.u4;
    __syncthreads();

    short8 af[4], bf[4];
#pragma unroll
    for (int t = 0; t < 4; ++t)
      af[t] = *(const short8*)(As + (t * 16 + l16) * 40 + quad * 8);
#pragma unroll
    for (int t = 0; t < 4; ++t) {
      int rr = w * 64 + t * 16 + l16;
      bf[t] = *(const short8*)(Bs + (rr * 4 + (quad ^ (rr & 3))) * 8);
    }
#pragma unroll
    for (int tm = 0; tm < 4; ++tm)
#pragma unroll
      for (int tn = 0; tn < 4; ++tn)
        acc[tm][tn] = __builtin_amdgcn_mfma_f32_16x16x32_bf16(af[tm], bf[tn], acc[tm][tn], 0, 0, 0);
  }

  float bias[4];
#pragma unroll
  for (int tn = 0; tn < 4; ++tn) bias[tn] = b1[w * 64 + tn * 16 + l16];

#pragma unroll
  for (int tm = 0; tm < 4; ++tm)
#pragma unroll
    for (int r = 0; r < 4; ++r) {
      int rl = tm * 16 + quad * 4 + r;         // tile-local row
      float w0 = swq[rl * 3 + 0], w1 = swq[rl * 3 + 1], w2 = swq[rl * 3 + 2];
      const float* g0 = G + (size_t)(bS + siq[rl * 3 + 0]) * COUT;
      const float* g1 = G + (size_t)(bS + siq[rl * 3 + 1]) * COUT;
      const float* g2 = G + (size_t)(bS + siq[rl * 3 + 2]) * COUT;
#pragma unroll
      for (int tn = 0; tn < 4; ++tn) {
        int col = w * 64 + tn * 16 + l16;
        float gv = fmaf(w0, g0[col], fmaf(w1, g1[col], w2 * g2[col]));
        float v = acc[tm][tn][r] + bias[tn] + gv;
        v = v > 0.f ? v : 0.f;
        H[(size_t)(m0 + rl) * COUT + col] = f2bf(v);
      }
    }
}

// ---------------------------------------------------------------------------
// K4: GEMM2 + bias + LayerNorm (R6 version: tile 64x256, BK=64, grid 512).
// ---------------------------------------------------------------------------
__global__ __launch_bounds__(256, 2) void gemm2_ln_kernel(const u16* __restrict__ H,
                                                          const u16* __restrict__ Bt,
                                                          const float* __restrict__ b2,
                                                          const float* __restrict__ gamma,
                                                          const float* __restrict__ beta,
                                                          float* __restrict__ out) {
  __shared__ u16 As[64 * 64];
  __shared__ u16 Bs[256 * 64];
  __shared__ float red[4][64][2];
  __shared__ float stats[64][2];
  int tid = threadIdx.x;
  int m0 = blockIdx.x << 6;
  int w = tid >> 6, lane = tid & 63;
  int quad = lane >> 4, l16 = lane & 15;

  f32x4 zero = {0.f, 0.f, 0.f, 0.f};
  f32x4 acc[4][4];
#pragma unroll
  for (int tm = 0; tm < 4; ++tm)
#pragma unroll
    for (int tn = 0; tn < 4; ++tn) acc[tm][tn] = zero;

  for (int kc = 0; kc < 4; ++kc) {
    __syncthreads();
#pragma unroll
    for (int r = 0; r < 2; ++r) {
      int u = tid + r * 256;
      int row = u >> 3, c = u & 7;
      int cg = c ^ (row & 7);
      gl_lds16(H + (size_t)(m0 + row) * COUT + kc * 64 + cg * 8, (char*)As + u * 16);
    }
#pragma unroll
    for (int r = 0; r < 8; ++r) {
      int u = tid + r * 256;
      int nrow = u >> 3, c = u & 7;
      int cg = c ^ (nrow & 7);
      gl_lds16(Bt + (size_t)nrow * COUT + kc * 64 + cg * 8, (char*)Bs + u * 16);
    }
    __syncthreads();

#pragma unroll
    for (int ko = 0; ko < 2; ++ko) {
      int ck = ko * 4 + quad;
      short8 af[4], bf[4];
#pragma unroll
      for (int t = 0; t < 4; ++t) {
        int ra = t * 16 + l16;
        af[t] = *(const short8*)(As + (ra * 8 + (ck ^ (ra & 7))) * 8);
      }
#pragma unroll
      for (int t = 0; t < 4; ++t) {
        int rr = w * 64 + t * 16 + l16;
        bf[t] = *(const short8*)(Bs + (rr * 8 + (ck ^ (rr & 7))) * 8);
      }
#pragma unroll
      for (int tm = 0; tm < 4; ++tm)
#pragma unroll
        for (int tn = 0; tn < 4; ++tn)
          acc[tm][tn] = __builtin_amdgcn_mfma_f32_16x16x32_bf16(af[tm], bf[tn], acc[tm][tn], 0, 0, 0);
    }
  }

  float bias[4], g[4], be[4];
#pragma unroll
  for (int tn = 0; tn < 4; ++tn) {
    int col = w * 64 + tn * 16 + l16;
    bias[tn] = b2[col]; g[tn] = gamma[col]; be[tn] = beta[col];
  }
#pragma unroll
  for (int tm = 0; tm < 4; ++tm)
#pragma unroll
    for (int r = 0; r < 4; ++r) {
      float s = 0.f, sq = 0.f;
#pragma unroll
      for (int tn = 0; tn < 4; ++tn) {
        float v = acc[tm][tn][r] + bias[tn];
        acc[tm][tn][r] = v;
        s += v; sq += v * v;
      }
#pragma unroll
      for (int msk = 1; msk < 16; msk <<= 1) {
        s += __shfl_xor(s, msk);
        sq += __shfl_xor(sq, msk);
      }
      if (l16 == 0) {
        int rl = tm * 16 + quad * 4 + r;
        red[w][rl][0] = s;
        red[w][rl][1] = sq;
      }
    }
  __syncthreads();
  if (tid < 64) {
    float s = red[0][tid][0] + red[1][tid][0] + red[2][tid][0] + red[3][tid][0];
    float sq = red[0][tid][1] + red[1][tid][1] + red[2][tid][1] + red[3][tid][1];
    float mu = s * (1.f / 256.f);
    float var = sq * (1.f / 256.f) - mu * mu;
    stats[tid][0] = mu;
    stats[tid][1] = rsqrtf(var + 1e-5f);
  }
  __syncthreads();
#pragma unroll
  for (int tm = 0; tm < 4; ++tm)
#pragma unroll
    for (int r = 0; r < 4; ++r) {
      int rl = tm * 16 + quad * 4 + r;
      float mu = stats[rl][0], rstd = stats[rl][1];
#pragma unroll
      for (int tn = 0; tn < 4; ++tn) {
        int col = w * 64 + tn * 16 + l16;
        out[(size_t)(m0 + rl) * COUT + col] = (acc[tm][tn][r] - mu) * rstd * g[tn] + be[tn];
      }
    }
}

// ---------------------------------------------------------------------------
extern "C" void kernel_launch(void* const* d_in, const int* in_sizes, int n_in,
                              void* d_out, int out_size, void* d_ws, size_t ws_size,
                              hipStream_t stream) {
  const float* xyz_hi    = (const float*)d_in[0];
  const float* xyz_lo    = (const float*)d_in[1];
  const float* feat_skip = (const float*)d_in[2];
  const float* feat_lo   = (const float*)d_in[3];
  const float* W1        = (const float*)d_in[4];
  const float* b1        = (const float*)d_in[5];
  const float* W2        = (const float*)d_in[6];
  const float* b2        = (const float*)d_in[7];
  const float* gamma     = (const float*)d_in[8];
  const float* beta      = (const float*)d_in[9];
  float* out = (float*)d_out;

  char* ws = (char*)d_ws;
  u16*   H     = (u16*)ws;                       // 16777216
  u16*   W1aT  = (u16*)(ws + 16777216);          // 131072
  u16*   W1bT  = (u16*)(ws + 16908288);          // 262144
  u16*   W2T   = (u16*)(ws + 17170432);          // 131072
  float* wq_g  = (float*)(ws + 17301504);        // 393216
  int*   iq_g  = (int*)(ws + 17694720);          // 393216
  float* G     = (float*)(ws + 18087936);        // 8388608

  wconv_kernel<<<1024, 256, 0, stream>>>(W1, W2, W1aT, W1bT, W2T);
  knn_kernel<<<MTOT / 64, 512, 0, stream>>>(xyz_hi, xyz_lo, wq_g, iq_g);
  ggemm_kernel<<<(BB * SS) / 32, 256, 0, stream>>>(feat_lo, W1bT, G);
  gemm1p_kernel<<<MTOT / 64, 256, 0, stream>>>(feat_skip, W1aT, b1, G, wq_g, iq_g, H);
  gemm2_ln_kernel<<<MTOT / 64, 256, 0, stream>>>(H, W2T, b2, gamma, beta, out);
}

// Round 9
// 187.634 us; speedup vs baseline: 1.1077x; 1.0148x over previous
//
#include <hip/hip_runtime.h>
#include <hip/hip_bf16.h>
#include <stdint.h>

typedef unsigned short u16;
typedef __attribute__((ext_vector_type(8))) short short8;
typedef __attribute__((ext_vector_type(4))) float f32x4;

#define BB 4
#define NN 8192
#define SS 2048
#define MTOT 32768
#define CSKIP 256
#define CLO 512
#define CIN 768
#define COUT 256

__device__ __forceinline__ u16 f2bf(float f) {
  unsigned u = __float_as_uint(f);
  u += 0x7fffu + ((u >> 16) & 1u);
  return (u16)(u >> 16);
}

__device__ __forceinline__ void gl_lds16(const void* g, void* l) {
  __builtin_amdgcn_global_load_lds(
      (const __attribute__((address_space(1))) void*)g,
      (__attribute__((address_space(3))) void*)l, 16, 0, 0);
}

// ---------------------------------------------------------------------------
// K0: weights -> bf16 transposed.  W1 split: W1a = W1[0:256,:] (skip part),
// W1b = W1[256:768,:] (interp part).  W1aT[n][k<256], W1bT[n][k<512], W2T.
// ---------------------------------------------------------------------------
__global__ __launch_bounds__(256) void wconv_kernel(const float* __restrict__ W1,
                                                    const float* __restrict__ W2,
                                                    u16* __restrict__ W1aT,
                                                    u16* __restrict__ W1bT,
                                                    u16* __restrict__ W2T) {
  int i = blockIdx.x * 256 + threadIdx.x;
  if (i < 65536) {                       // W1aT: n=i>>8, k=i&255
    int n = i >> 8, k = i & 255;
    W1aT[i] = f2bf(W1[(size_t)k * COUT + n]);
  } else if (i < 65536 + 131072) {       // W1bT: n=j>>9, k=j&511
    int j = i - 65536;
    int n = j >> 9, k = j & 511;
    W1bT[j] = f2bf(W1[(size_t)(256 + k) * COUT + n]);
  } else {                               // W2T
    int j = i - 65536 - 131072;
    int n = j >> 8, k = j & 255;
    W2T[j] = f2bf(W2[(size_t)k * COUT + n]);
  }
}

// ---------------------------------------------------------------------------
// K1: KNN (K=3), diff-form fp32 distances (expansion form flips near-ties —
// R3 failure). lane = query, wave = candidate-partition; LDS reads broadcast.
// Insert via min/med3 identity (3 value ops) + 3 cmp + 5 cndmask for indices
// (strict < => identical stable tie semantics; R8's swap chain was ~37
// VALU/pair, this is ~17).
// ---------------------------------------------------------------------------
__global__ __launch_bounds__(512) void knn_kernel(
    const float* __restrict__ xyz_hi, const float* __restrict__ xyz_lo,
    float* __restrict__ wq_g, int* __restrict__ iq_g) {
  __shared__ float4 sxyz[SS];
  __shared__ float md[8][64][3];
  __shared__ int   mi[8][64][3];

  int tid = threadIdx.x;
  int blk = blockIdx.x;
  int b = blk >> 7;
  const float* xl = xyz_lo + (size_t)b * SS * 3;
  for (int j = tid; j < SS; j += 512)
    sxyz[j] = make_float4(xl[j * 3 + 0], xl[j * 3 + 1], xl[j * 3 + 2], 0.f);
  __syncthreads();

  int wave = tid >> 6, lane = tid & 63;
  int qm = blk * 64 + lane;
  float qx = xyz_hi[(size_t)qm * 3 + 0];
  float qy = xyz_hi[(size_t)qm * 3 + 1];
  float qz = xyz_hi[(size_t)qm * 3 + 2];

  float b0 = 1e30f, b1 = 1e30f, b2 = 1e30f;
  int i0 = -1, i1 = -1, i2 = -1;
  int j0 = wave * 256;
#pragma unroll 8
  for (int jj = 0; jj < 256; ++jj) {
    int j = j0 + jj;
    float4 p = sxyz[j];
    float dx = p.x - qx, dy = p.y - qy, dz = p.z - qz;
    float d = fmaf(dx, dx, fmaf(dy, dy, dz * dz));
    bool c0 = d < b0, c1 = d < b1, c2 = d < b2;
    float nb0 = fminf(b0, d);
    float nb1 = __builtin_amdgcn_fmed3f(b0, b1, d);
    float nb2 = __builtin_amdgcn_fmed3f(b1, b2, d);
    int ni0 = c0 ? j : i0;
    int ni1 = c0 ? i0 : (c1 ? j : i1);
    int ni2 = c1 ? i1 : (c2 ? j : i2);
    b0 = nb0; b1 = nb1; b2 = nb2;
    i0 = ni0; i1 = ni1; i2 = ni2;
  }
  md[wave][lane][0] = b0; mi[wave][lane][0] = i0;
  md[wave][lane][1] = b1; mi[wave][lane][1] = i1;
  md[wave][lane][2] = b2; mi[wave][lane][2] = i2;
  __syncthreads();

  if (tid < 64) {
    int q = tid;
    float fb0 = 1e30f, fb1 = 1e30f, fb2 = 1e30f;
    int fi0 = -1, fi1 = -1, fi2 = -1;
    for (int p = 0; p < 8; ++p)
#pragma unroll
      for (int s = 0; s < 3; ++s) {
        float d = md[p][q][s]; int ix = mi[p][q][s];
        if (d < fb2 || (d == fb2 && ix < fi2)) {
          fb2 = d; fi2 = ix;
          if (fb2 < fb1 || (fb2 == fb1 && fi2 < fi1)) {
            float t = fb1; fb1 = fb2; fb2 = t; int ti = fi1; fi1 = fi2; fi2 = ti;
          }
          if (fb1 < fb0 || (fb1 == fb0 && fi1 < fi0)) {
            float t = fb0; fb0 = fb1; fb1 = t; int ti = fi0; fi0 = fi1; fi1 = ti;
          }
        }
      }
    int qm2 = blk * 64 + q;
    float d0 = sqrtf(fb0), d1 = sqrtf(fb1), d2 = sqrtf(fb2);
    float inv0 = 1.0f / (d0 + 1e-8f);
    float inv1 = 1.0f / (d1 + 1e-8f);
    float inv2 = 1.0f / (d2 + 1e-8f);
    float s = inv0 + inv1 + inv2;
    wq_g[(size_t)qm2 * 3 + 0] = inv0 / s;
    wq_g[(size_t)qm2 * 3 + 1] = inv1 / s;
    wq_g[(size_t)qm2 * 3 + 2] = inv2 / s;
    iq_g[(size_t)qm2 * 3 + 0] = fi0;
    iq_g[(size_t)qm2 * 3 + 1] = fi1;
    iq_g[(size_t)qm2 * 3 + 2] = fi2;
  }
}

// ---------------------------------------------------------------------------
// K2: ggemm — G = feat_lo @ W1b  (dense, M=8192, K=512, N=256, fp32 out).
// Tile 32x256, 256 thr, BK=32, grid 256.
// ---------------------------------------------------------------------------
__global__ __launch_bounds__(256, 4) void ggemm_kernel(
    const float* __restrict__ feat_lo, const u16* __restrict__ W1bT,
    float* __restrict__ G) {
  __shared__ u16 As[32 * 40];    // padded rows
  __shared__ u16 Bs[256 * 32];   // xor-swizzled 16B slots
  int tid = threadIdx.x;
  int m0 = blockIdx.x << 5;
  int w = tid >> 6, lane = tid & 63;
  int quad = lane >> 4, l16 = lane & 15;

  int srow = tid >> 3, s4 = (tid & 7) << 2;
  const float* arow = feat_lo + (size_t)(m0 + srow) * CLO + s4;
  u16* As_dst = As + srow * 40 + s4;

  f32x4 zero = {0.f, 0.f, 0.f, 0.f};
  f32x4 acc[2][4];
#pragma unroll
  for (int tm = 0; tm < 2; ++tm)
#pragma unroll
    for (int tn = 0; tn < 4; ++tn) acc[tm][tn] = zero;

  for (int kc = 0; kc < 16; ++kc) {
    __syncthreads();
#pragma unroll
    for (int r = 0; r < 4; ++r) {
      int u = tid + r * 256;
      int nrow = u >> 2, c = u & 3;
      int cg = c ^ (nrow & 3);
      gl_lds16(W1bT + (size_t)nrow * CLO + kc * 32 + cg * 8, (char*)Bs + u * 16);
    }
    float4 av = *(const float4*)(arow + kc * 32);
    union { __hip_bfloat162 h2[2]; uint2 u2; } pk;
    pk.h2[0] = __float22bfloat162_rn(make_float2(av.x, av.y));
    pk.h2[1] = __float22bfloat162_rn(make_float2(av.z, av.w));
    *(uint2*)As_dst = pk.u2;
    __syncthreads();

    short8 af[2], bf[4];
#pragma unroll
    for (int t = 0; t < 2; ++t)
      af[t] = *(const short8*)(As + (t * 16 + l16) * 40 + quad * 8);
#pragma unroll
    for (int t = 0; t < 4; ++t) {
      int rr = w * 64 + t * 16 + l16;
      bf[t] = *(const short8*)(Bs + (rr * 4 + (quad ^ (rr & 3))) * 8);
    }
#pragma unroll
    for (int tm = 0; tm < 2; ++tm)
#pragma unroll
      for (int tn = 0; tn < 4; ++tn)
        acc[tm][tn] = __builtin_amdgcn_mfma_f32_16x16x32_bf16(af[tm], bf[tn], acc[tm][tn], 0, 0, 0);
  }

#pragma unroll
  for (int tm = 0; tm < 2; ++tm)
#pragma unroll
    for (int tn = 0; tn < 4; ++tn) {
      int col = w * 64 + tn * 16 + l16;
#pragma unroll
      for (int r = 0; r < 4; ++r) {
        int row = m0 + tm * 16 + quad * 4 + r;
        G[(size_t)row * COUT + col] = acc[tm][tn][r];
      }
    }
}

// ---------------------------------------------------------------------------
// K3: gemm1' — H = relu(skip@W1a + b1 + sum_k wk*G[ik])  (bf16 out).
// Dense streaming A (feat_skip), K=256, tile 64x256, 256 thr, grid 512.
// IDW-gather moved to the epilogue: 3 fp32 reads/elem from L2-resident G.
// ---------------------------------------------------------------------------
__global__ __launch_bounds__(256, 2) void gemm1p_kernel(
    const float* __restrict__ feat_skip, const u16* __restrict__ W1aT,
    const float* __restrict__ b1, const float* __restrict__ G,
    const float* __restrict__ wq_g, const int* __restrict__ iq_g,
    u16* __restrict__ H) {
  __shared__ u16 As[64 * 40];    // 5 KB, padded rows
  __shared__ u16 Bs[256 * 32];   // 16 KB, xor-swizzled
  __shared__ float swq[192];
  __shared__ int   siq[192];
  int tid = threadIdx.x;
  int m0 = blockIdx.x << 6;
  int bS = (m0 >> 13) * SS;      // batch base row in G
  int w = tid >> 6, lane = tid & 63;
  int quad = lane >> 4, l16 = lane & 15;

  if (tid < 192) {
    swq[tid] = wq_g[(size_t)m0 * 3 + tid];
    siq[tid] = iq_g[(size_t)m0 * 3 + tid];
  }

  int srow = tid >> 2, sc8 = (tid & 3) << 3;
  const float* arow = feat_skip + (size_t)(m0 + srow) * CSKIP + sc8;
  u16* As_dst = As + srow * 40 + sc8;

  f32x4 zero = {0.f, 0.f, 0.f, 0.f};
  f32x4 acc[4][4];
#pragma unroll
  for (int tm = 0; tm < 4; ++tm)
#pragma unroll
    for (int tn = 0; tn < 4; ++tn) acc[tm][tn] = zero;

  for (int kc = 0; kc < 8; ++kc) {
    __syncthreads();
#pragma unroll
    for (int r = 0; r < 4; ++r) {
      int u = tid + r * 256;
      int nrow = u >> 2, c = u & 3;
      int cg = c ^ (nrow & 3);
      gl_lds16(W1aT + (size_t)nrow * CSKIP + kc * 32 + cg * 8, (char*)Bs + u * 16);
    }
    float4 x0 = *(const float4*)(arow + kc * 32);
    float4 x1 = *(const float4*)(arow + kc * 32 + 4);
    union { __hip_bfloat162 h2[4]; uint4 u4; } pk;
    pk.h2[0] = __float22bfloat162_rn(make_float2(x0.x, x0.y));
    pk.h2[1] = __float22bfloat162_rn(make_float2(x0.z, x0.w));
    pk.h2[2] = __float22bfloat162_rn(make_float2(x1.x, x1.y));
    pk.h2[3] = __float22bfloat162_rn(make_float2(x1.z, x1.w));
    *(uint4*)As_dst = pk.u4;
    __syncthreads();

    short8 af[4], bf[4];
#pragma unroll
    for (int t = 0; t < 4; ++t)
      af[t] = *(const short8*)(As + (t * 16 + l16) * 40 + quad * 8);
#pragma unroll
    for (int t = 0; t < 4; ++t) {
      int rr = w * 64 + t * 16 + l16;
      bf[t] = *(const short8*)(Bs + (rr * 4 + (quad ^ (rr & 3))) * 8);
    }
#pragma unroll
    for (int tm = 0; tm < 4; ++tm)
#pragma unroll
      for (int tn = 0; tn < 4; ++tn)
        acc[tm][tn] = __builtin_amdgcn_mfma_f32_16x16x32_bf16(af[tm], bf[tn], acc[tm][tn], 0, 0, 0);
  }

  float bias[4];
#pragma unroll
  for (int tn = 0; tn < 4; ++tn) bias[tn] = b1[w * 64 + tn * 16 + l16];

#pragma unroll
  for (int tm = 0; tm < 4; ++tm)
#pragma unroll
    for (int r = 0; r < 4; ++r) {
      int rl = tm * 16 + quad * 4 + r;         // tile-local row
      float w0 = swq[rl * 3 + 0], w1 = swq[rl * 3 + 1], w2 = swq[rl * 3 + 2];
      const float* g0 = G + (size_t)(bS + siq[rl * 3 + 0]) * COUT;
      const float* g1 = G + (size_t)(bS + siq[rl * 3 + 1]) * COUT;
      const float* g2 = G + (size_t)(bS + siq[rl * 3 + 2]) * COUT;
#pragma unroll
      for (int tn = 0; tn < 4; ++tn) {
        int col = w * 64 + tn * 16 + l16;
        float gv = fmaf(w0, g0[col], fmaf(w1, g1[col], w2 * g2[col]));
        float v = acc[tm][tn][r] + bias[tn] + gv;
        v = v > 0.f ? v : 0.f;
        H[(size_t)(m0 + rl) * COUT + col] = f2bf(v);
      }
    }
}

// ---------------------------------------------------------------------------
// K4: GEMM2 + bias + LayerNorm (tile 64x256, BK=64, grid 512).
// ---------------------------------------------------------------------------
__global__ __launch_bounds__(256, 2) void gemm2_ln_kernel(const u16* __restrict__ H,
                                                          const u16* __restrict__ Bt,
                                                          const float* __restrict__ b2,
                                                          const float* __restrict__ gamma,
                                                          const float* __restrict__ beta,
                                                          float* __restrict__ out) {
  __shared__ u16 As[64 * 64];
  __shared__ u16 Bs[256 * 64];
  __shared__ float red[4][64][2];
  __shared__ float stats[64][2];
  int tid = threadIdx.x;
  int m0 = blockIdx.x << 6;
  int w = tid >> 6, lane = tid & 63;
  int quad = lane >> 4, l16 = lane & 15;

  f32x4 zero = {0.f, 0.f, 0.f, 0.f};
  f32x4 acc[4][4];
#pragma unroll
  for (int tm = 0; tm < 4; ++tm)
#pragma unroll
    for (int tn = 0; tn < 4; ++tn) acc[tm][tn] = zero;

  for (int kc = 0; kc < 4; ++kc) {
    __syncthreads();
#pragma unroll
    for (int r = 0; r < 2; ++r) {
      int u = tid + r * 256;
      int row = u >> 3, c = u & 7;
      int cg = c ^ (row & 7);
      gl_lds16(H + (size_t)(m0 + row) * COUT + kc * 64 + cg * 8, (char*)As + u * 16);
    }
#pragma unroll
    for (int r = 0; r < 8; ++r) {
      int u = tid + r * 256;
      int nrow = u >> 3, c = u & 7;
      int cg = c ^ (nrow & 7);
      gl_lds16(Bt + (size_t)nrow * COUT + kc * 64 + cg * 8, (char*)Bs + u * 16);
    }
    __syncthreads();

#pragma unroll
    for (int ko = 0; ko < 2; ++ko) {
      int ck = ko * 4 + quad;
      short8 af[4], bf[4];
#pragma unroll
      for (int t = 0; t < 4; ++t) {
        int ra = t * 16 + l16;
        af[t] = *(const short8*)(As + (ra * 8 + (ck ^ (ra & 7))) * 8);
      }
#pragma unroll
      for (int t = 0; t < 4; ++t) {
        int rr = w * 64 + t * 16 + l16;
        bf[t] = *(const short8*)(Bs + (rr * 8 + (ck ^ (rr & 7))) * 8);
      }
#pragma unroll
      for (int tm = 0; tm < 4; ++tm)
#pragma unroll
        for (int tn = 0; tn < 4; ++tn)
          acc[tm][tn] = __builtin_amdgcn_mfma_f32_16x16x32_bf16(af[tm], bf[tn], acc[tm][tn], 0, 0, 0);
    }
  }

  float bias[4], g[4], be[4];
#pragma unroll
  for (int tn = 0; tn < 4; ++tn) {
    int col = w * 64 + tn * 16 + l16;
    bias[tn] = b2[col]; g[tn] = gamma[col]; be[tn] = beta[col];
  }
#pragma unroll
  for (int tm = 0; tm < 4; ++tm)
#pragma unroll
    for (int r = 0; r < 4; ++r) {
      float s = 0.f, sq = 0.f;
#pragma unroll
      for (int tn = 0; tn < 4; ++tn) {
        float v = acc[tm][tn][r] + bias[tn];
        acc[tm][tn][r] = v;
        s += v; sq += v * v;
      }
#pragma unroll
      for (int msk = 1; msk < 16; msk <<= 1) {
        s += __shfl_xor(s, msk);
        sq += __shfl_xor(sq, msk);
      }
      if (l16 == 0) {
        int rl = tm * 16 + quad * 4 + r;
        red[w][rl][0] = s;
        red[w][rl][1] = sq;
      }
    }
  __syncthreads();
  if (tid < 64) {
    float s = red[0][tid][0] + red[1][tid][0] + red[2][tid][0] + red[3][tid][0];
    float sq = red[0][tid][1] + red[1][tid][1] + red[2][tid][1] + red[3][tid][1];
    float mu = s * (1.f / 256.f);
    float var = sq * (1.f / 256.f) - mu * mu;
    stats[tid][0] = mu;
    stats[tid][1] = rsqrtf(var + 1e-5f);
  }
  __syncthreads();
#pragma unroll
  for (int tm = 0; tm < 4; ++tm)
#pragma unroll
    for (int r = 0; r < 4; ++r) {
      int rl = tm * 16 + quad * 4 + r;
      float mu = stats[rl][0], rstd = stats[rl][1];
#pragma unroll
      for (int tn = 0; tn < 4; ++tn) {
        int col = w * 64 + tn * 16 + l16;
        out[(size_t)(m0 + rl) * COUT + col] = (acc[tm][tn][r] - mu) * rstd * g[tn] + be[tn];
      }
    }
}

// ---------------------------------------------------------------------------
extern "C" void kernel_launch(void* const* d_in, const int* in_sizes, int n_in,
                              void* d_out, int out_size, void* d_ws, size_t ws_size,
                              hipStream_t stream) {
  const float* xyz_hi    = (const float*)d_in[0];
  const float* xyz_lo    = (const float*)d_in[1];
  const float* feat_skip = (const float*)d_in[2];
  const float* feat_lo   = (const float*)d_in[3];
  const float* W1        = (const float*)d_in[4];
  const float* b1        = (const float*)d_in[5];
  const float* W2        = (const float*)d_in[6];
  const float* b2        = (const float*)d_in[7];
  const float* gamma     = (const float*)d_in[8];
  const float* beta      = (const float*)d_in[9];
  float* out = (float*)d_out;

  char* ws = (char*)d_ws;
  u16*   H     = (u16*)ws;                       // 16777216
  u16*   W1aT  = (u16*)(ws + 16777216);          // 131072
  u16*   W1bT  = (u16*)(ws + 16908288);          // 262144
  u16*   W2T   = (u16*)(ws + 17170432);          // 131072
  float* wq_g  = (float*)(ws + 17301504);        // 393216
  int*   iq_g  = (int*)(ws + 17694720);          // 393216
  float* G     = (float*)(ws + 18087936);        // 8388608

  wconv_kernel<<<1024, 256, 0, stream>>>(W1, W2, W1aT, W1bT, W2T);
  knn_kernel<<<MTOT / 64, 512, 0, stream>>>(xyz_hi, xyz_lo, wq_g, iq_g);
  ggemm_kernel<<<(BB * SS) / 32, 256, 0, stream>>>(feat_lo, W1bT, G);
  gemm1p_kernel<<<MTOT / 64, 256, 0, stream>>>(feat_skip, W1aT, b1, G, wq_g, iq_g, H);
  gemm2_ln_kernel<<<MTOT / 64, 256, 0, stream>>>(H, W2T, b2, gamma, beta, out);
}

// Round 10
// 185.894 us; speedup vs baseline: 1.1181x; 1.0094x over previous
//
#include <hip/hip_runtime.h>
#include <hip/hip_bf16.h>
#include <stdint.h>

typedef unsigned short u16;
typedef __attribute__((ext_vector_type(8))) short short8;
typedef __attribute__((ext_vector_type(4))) float f32x4;

#define BB 4
#define NN 8192
#define SS 2048
#define MTOT 32768
#define CSKIP 256
#define CLO 512
#define CIN 768
#define COUT 256

__device__ __forceinline__ u16 f2bf(float f) {
  unsigned u = __float_as_uint(f);
  u += 0x7fffu + ((u >> 16) & 1u);
  return (u16)(u >> 16);
}

__device__ __forceinline__ void gl_lds16(const void* g, void* l) {
  __builtin_amdgcn_global_load_lds(
      (const __attribute__((address_space(1))) void*)g,
      (__attribute__((address_space(3))) void*)l, 16, 0, 0);
}

// ---------------------------------------------------------------------------
// K1: blocks 0..511 = KNN (K=3, diff-form fp32, branchy med3 insert);
//     blocks 512..639 = weight conversion (W1aT / W1bT / W2T), grid-stride.
// Merged to save a launch: outputs disjoint, both consume only inputs.
// ---------------------------------------------------------------------------
__global__ __launch_bounds__(512) void knn_wconv_kernel(
    const float* __restrict__ xyz_hi, const float* __restrict__ xyz_lo,
    const float* __restrict__ W1, const float* __restrict__ W2,
    float* __restrict__ wq_g, int* __restrict__ iq_g,
    u16* __restrict__ W1aT, u16* __restrict__ W1bT, u16* __restrict__ W2T) {
  int blk = blockIdx.x;
  if (blk >= 512) {
    // ---- wconv path: 262144 elements over 128 blocks x 512 thr (4 iters) ----
    int base = (blk - 512) * 512 + threadIdx.x;
    for (int i = base; i < 262144; i += 65536) {
      if (i < 65536) {                       // W1aT: n=i>>8, k=i&255
        int n = i >> 8, k = i & 255;
        W1aT[i] = f2bf(W1[(size_t)k * COUT + n]);
      } else if (i < 196608) {               // W1bT: n=j>>9, k=j&511
        int j = i - 65536;
        int n = j >> 9, k = j & 511;
        W1bT[j] = f2bf(W1[(size_t)(256 + k) * COUT + n]);
      } else {                               // W2T
        int j = i - 196608;
        int n = j >> 8, k = j & 255;
        W2T[j] = f2bf(W2[(size_t)k * COUT + n]);
      }
    }
    return;
  }

  // ---- knn path ----
  __shared__ float4 sxyz[SS];
  __shared__ float md[8][64][3];
  __shared__ int   mi[8][64][3];

  int tid = threadIdx.x;
  int b = blk >> 7;
  const float* xl = xyz_lo + (size_t)b * SS * 3;
  for (int j = tid; j < SS; j += 512)
    sxyz[j] = make_float4(xl[j * 3 + 0], xl[j * 3 + 1], xl[j * 3 + 2], 0.f);
  __syncthreads();

  int wave = tid >> 6, lane = tid & 63;
  int qm = blk * 64 + lane;
  float qx = xyz_hi[(size_t)qm * 3 + 0];
  float qy = xyz_hi[(size_t)qm * 3 + 1];
  float qz = xyz_hi[(size_t)qm * 3 + 2];

  float b0 = 1e30f, b1 = 1e30f, b2 = 1e30f;
  int i0 = -1, i1 = -1, i2 = -1;
  int j0 = wave * 256;
#pragma unroll 4
  for (int jj = 0; jj < 256; ++jj) {
    int j = j0 + jj;
    float4 p = sxyz[j];
    float dx = p.x - qx, dy = p.y - qy, dz = p.z - qz;
    float d = fmaf(dx, dx, fmaf(dy, dy, dz * dz));
    if (d < b2) {                     // exec-skipped ~70% of iters
      bool c0 = d < b0, c1 = d < b1;
      float nb0 = fminf(b0, d);
      float nb1 = __builtin_amdgcn_fmed3f(b0, b1, d);
      float nb2 = c1 ? b1 : d;        // med3(b1,b2,d) given d<b2
      i2 = c1 ? i1 : j;               // order matters: i2 uses old i1
      i1 = c0 ? i0 : (c1 ? j : i1);   // i1 uses old i0
      i0 = c0 ? j : i0;
      b0 = nb0; b1 = nb1; b2 = nb2;
    }
  }
  md[wave][lane][0] = b0; mi[wave][lane][0] = i0;
  md[wave][lane][1] = b1; mi[wave][lane][1] = i1;
  md[wave][lane][2] = b2; mi[wave][lane][2] = i2;
  __syncthreads();

  if (tid < 64) {
    int q = tid;
    float fb0 = 1e30f, fb1 = 1e30f, fb2 = 1e30f;
    int fi0 = -1, fi1 = -1, fi2 = -1;
    for (int p = 0; p < 8; ++p)
#pragma unroll
      for (int s = 0; s < 3; ++s) {
        float d = md[p][q][s]; int ix = mi[p][q][s];
        if (d < fb2 || (d == fb2 && ix < fi2)) {
          fb2 = d; fi2 = ix;
          if (fb2 < fb1 || (fb2 == fb1 && fi2 < fi1)) {
            float t = fb1; fb1 = fb2; fb2 = t; int ti = fi1; fi1 = fi2; fi2 = ti;
          }
          if (fb1 < fb0 || (fb1 == fb0 && fi1 < fi0)) {
            float t = fb0; fb0 = fb1; fb1 = t; int ti = fi0; fi0 = fi1; fi1 = ti;
          }
        }
      }
    int qm2 = blk * 64 + q;
    float d0 = sqrtf(fb0), d1 = sqrtf(fb1), d2 = sqrtf(fb2);
    float inv0 = 1.0f / (d0 + 1e-8f);
    float inv1 = 1.0f / (d1 + 1e-8f);
    float inv2 = 1.0f / (d2 + 1e-8f);
    float s = inv0 + inv1 + inv2;
    wq_g[(size_t)qm2 * 3 + 0] = inv0 / s;
    wq_g[(size_t)qm2 * 3 + 1] = inv1 / s;
    wq_g[(size_t)qm2 * 3 + 2] = inv2 / s;
    iq_g[(size_t)qm2 * 3 + 0] = fi0;
    iq_g[(size_t)qm2 * 3 + 1] = fi1;
    iq_g[(size_t)qm2 * 3 + 2] = fi2;
  }
}

// ---------------------------------------------------------------------------
// K2: ggemm — G = feat_lo @ W1b  (dense, M=8192, K=512, N=256, fp32 out).
// Tile 32x256, 256 thr, BK=32, grid 256.
// ---------------------------------------------------------------------------
__global__ __launch_bounds__(256, 4) void ggemm_kernel(
    const float* __restrict__ feat_lo, const u16* __restrict__ W1bT,
    float* __restrict__ G) {
  __shared__ u16 As[32 * 40];
  __shared__ u16 Bs[256 * 32];
  int tid = threadIdx.x;
  int m0 = blockIdx.x << 5;
  int w = tid >> 6, lane = tid & 63;
  int quad = lane >> 4, l16 = lane & 15;

  int srow = tid >> 3, s4 = (tid & 7) << 2;
  const float* arow = feat_lo + (size_t)(m0 + srow) * CLO + s4;
  u16* As_dst = As + srow * 40 + s4;

  f32x4 zero = {0.f, 0.f, 0.f, 0.f};
  f32x4 acc[2][4];
#pragma unroll
  for (int tm = 0; tm < 2; ++tm)
#pragma unroll
    for (int tn = 0; tn < 4; ++tn) acc[tm][tn] = zero;

  for (int kc = 0; kc < 16; ++kc) {
    __syncthreads();
#pragma unroll
    for (int r = 0; r < 4; ++r) {
      int u = tid + r * 256;
      int nrow = u >> 2, c = u & 3;
      int cg = c ^ (nrow & 3);
      gl_lds16(W1bT + (size_t)nrow * CLO + kc * 32 + cg * 8, (char*)Bs + u * 16);
    }
    float4 av = *(const float4*)(arow + kc * 32);
    union { __hip_bfloat162 h2[2]; uint2 u2; } pk;
    pk.h2[0] = __float22bfloat162_rn(make_float2(av.x, av.y));
    pk.h2[1] = __float22bfloat162_rn(make_float2(av.z, av.w));
    *(uint2*)As_dst = pk.u2;
    __syncthreads();

    short8 af[2], bf[4];
#pragma unroll
    for (int t = 0; t < 2; ++t)
      af[t] = *(const short8*)(As + (t * 16 + l16) * 40 + quad * 8);
#pragma unroll
    for (int t = 0; t < 4; ++t) {
      int rr = w * 64 + t * 16 + l16;
      bf[t] = *(const short8*)(Bs + (rr * 4 + (quad ^ (rr & 3))) * 8);
    }
#pragma unroll
    for (int tm = 0; tm < 2; ++tm)
#pragma unroll
      for (int tn = 0; tn < 4; ++tn)
        acc[tm][tn] = __builtin_amdgcn_mfma_f32_16x16x32_bf16(af[tm], bf[tn], acc[tm][tn], 0, 0, 0);
  }

#pragma unroll
  for (int tm = 0; tm < 2; ++tm)
#pragma unroll
    for (int tn = 0; tn < 4; ++tn) {
      int col = w * 64 + tn * 16 + l16;
#pragma unroll
      for (int r = 0; r < 4; ++r) {
        int row = m0 + tm * 16 + quad * 4 + r;
        G[(size_t)row * COUT + col] = acc[tm][tn][r];
      }
    }
}

// ---------------------------------------------------------------------------
// K3: fused MLP — phase 1: Htile = relu(skip@W1a + b1 + IDW-gather(G)) -> LDS
// (bf16, rows padded to 264); phase 2: out = LN(Htile@W2 + b2). One kernel:
// kills the H HBM round-trip and a launch. Tile 64x256, 256 thr, grid 512.
// ---------------------------------------------------------------------------
__global__ __launch_bounds__(256, 2) void gemm12_kernel(
    const float* __restrict__ feat_skip, const u16* __restrict__ W1aT,
    const float* __restrict__ b1, const float* __restrict__ G,
    const float* __restrict__ wq_g, const int* __restrict__ iq_g,
    const u16* __restrict__ W2T, const float* __restrict__ b2,
    const float* __restrict__ gamma, const float* __restrict__ beta,
    float* __restrict__ out) {
  __shared__ u16 Hs[64 * 264];   // 33 KB, row pad 8 -> 2-way max on ds_read
  __shared__ u16 Bs[256 * 32];   // 16 KB: W1a chunks (ph1), W2 chunks (ph2)
  __shared__ u16 As[64 * 40];    // 5 KB (ph1 A staging)
  __shared__ float swq[192];
  __shared__ int   siq[192];
  __shared__ float red[4][64][2];
  __shared__ float stats[64][2];
  int tid = threadIdx.x;
  int m0 = blockIdx.x << 6;
  int bS = (m0 >> 13) * SS;
  int w = tid >> 6, lane = tid & 63;
  int quad = lane >> 4, l16 = lane & 15;

  if (tid < 192) {
    swq[tid] = wq_g[(size_t)m0 * 3 + tid];
    siq[tid] = iq_g[(size_t)m0 * 3 + tid];
  }

  int srow = tid >> 2, sc8 = (tid & 3) << 3;
  const float* arow = feat_skip + (size_t)(m0 + srow) * CSKIP + sc8;
  u16* As_dst = As + srow * 40 + sc8;

  f32x4 zero = {0.f, 0.f, 0.f, 0.f};
  f32x4 acc[4][4];
#pragma unroll
  for (int tm = 0; tm < 4; ++tm)
#pragma unroll
    for (int tn = 0; tn < 4; ++tn) acc[tm][tn] = zero;

  // ---- phase 1: skip @ W1a ----
  for (int kc = 0; kc < 8; ++kc) {
    __syncthreads();
#pragma unroll
    for (int r = 0; r < 4; ++r) {
      int u = tid + r * 256;
      int nrow = u >> 2, c = u & 3;
      int cg = c ^ (nrow & 3);
      gl_lds16(W1aT + (size_t)nrow * CSKIP + kc * 32 + cg * 8, (char*)Bs + u * 16);
    }
    float4 x0 = *(const float4*)(arow + kc * 32);
    float4 x1 = *(const float4*)(arow + kc * 32 + 4);
    union { __hip_bfloat162 h2[4]; uint4 u4; } pk;
    pk.h2[0] = __float22bfloat162_rn(make_float2(x0.x, x0.y));
    pk.h2[1] = __float22bfloat162_rn(make_float2(x0.z, x0.w));
    pk.h2[2] = __float22bfloat162_rn(make_float2(x1.x, x1.y));
    pk.h2[3] = __float22bfloat162_rn(make_float2(x1.z, x1.w));
    *(uint4*)As_dst = pk.u4;
    __syncthreads();

    short8 af[4], bf[4];
#pragma unroll
    for (int t = 0; t < 4; ++t)
      af[t] = *(const short8*)(As + (t * 16 + l16) * 40 + quad * 8);
#pragma unroll
    for (int t = 0; t < 4; ++t) {
      int rr = w * 64 + t * 16 + l16;
      bf[t] = *(const short8*)(Bs + (rr * 4 + (quad ^ (rr & 3))) * 8);
    }
#pragma unroll
    for (int tm = 0; tm < 4; ++tm)
#pragma unroll
      for (int tn = 0; tn < 4; ++tn)
        acc[tm][tn] = __builtin_amdgcn_mfma_f32_16x16x32_bf16(af[tm], bf[tn], acc[tm][tn], 0, 0, 0);
  }

  // ---- phase 1 epilogue: bias + IDW gather + relu -> Hs (bf16 in LDS) ----
  {
    float bias[4];
#pragma unroll
    for (int tn = 0; tn < 4; ++tn) bias[tn] = b1[w * 64 + tn * 16 + l16];
#pragma unroll
    for (int tm = 0; tm < 4; ++tm)
#pragma unroll
      for (int r = 0; r < 4; ++r) {
        int rl = tm * 16 + quad * 4 + r;
        float w0 = swq[rl * 3 + 0], w1 = swq[rl * 3 + 1], w2 = swq[rl * 3 + 2];
        const float* g0 = G + (size_t)(bS + siq[rl * 3 + 0]) * COUT;
        const float* g1 = G + (size_t)(bS + siq[rl * 3 + 1]) * COUT;
        const float* g2 = G + (size_t)(bS + siq[rl * 3 + 2]) * COUT;
#pragma unroll
        for (int tn = 0; tn < 4; ++tn) {
          int col = w * 64 + tn * 16 + l16;
          float gv = fmaf(w0, g0[col], fmaf(w1, g1[col], w2 * g2[col]));
          float v = acc[tm][tn][r] + bias[tn] + gv;
          v = v > 0.f ? v : 0.f;
          Hs[rl * 264 + col] = f2bf(v);
        }
      }
  }

  // ---- phase 2: Hs @ W2 + LN ----
#pragma unroll
  for (int tm = 0; tm < 4; ++tm)
#pragma unroll
    for (int tn = 0; tn < 4; ++tn) acc[tm][tn] = zero;

  for (int kc = 0; kc < 8; ++kc) {
    __syncthreads();                 // 1st iter: Hs writes + last ph1 Bs reads done
#pragma unroll
    for (int r = 0; r < 4; ++r) {
      int u = tid + r * 256;
      int nrow = u >> 2, c = u & 3;
      int cg = c ^ (nrow & 3);
      gl_lds16(W2T + (size_t)nrow * COUT + kc * 32 + cg * 8, (char*)Bs + u * 16);
    }
    __syncthreads();

    short8 af[4], bf[4];
#pragma unroll
    for (int t = 0; t < 4; ++t)
      af[t] = *(const short8*)(Hs + (t * 16 + l16) * 264 + kc * 32 + quad * 8);
#pragma unroll
    for (int t = 0; t < 4; ++t) {
      int rr = w * 64 + t * 16 + l16;
      bf[t] = *(const short8*)(Bs + (rr * 4 + (quad ^ (rr & 3))) * 8);
    }
#pragma unroll
    for (int tm = 0; tm < 4; ++tm)
#pragma unroll
      for (int tn = 0; tn < 4; ++tn)
        acc[tm][tn] = __builtin_amdgcn_mfma_f32_16x16x32_bf16(af[tm], bf[tn], acc[tm][tn], 0, 0, 0);
  }

  float bias[4], g[4], be[4];
#pragma unroll
  for (int tn = 0; tn < 4; ++tn) {
    int col = w * 64 + tn * 16 + l16;
    bias[tn] = b2[col]; g[tn] = gamma[col]; be[tn] = beta[col];
  }
#pragma unroll
  for (int tm = 0; tm < 4; ++tm)
#pragma unroll
    for (int r = 0; r < 4; ++r) {
      float s = 0.f, sq = 0.f;
#pragma unroll
      for (int tn = 0; tn < 4; ++tn) {
        float v = acc[tm][tn][r] + bias[tn];
        acc[tm][tn][r] = v;
        s += v; sq += v * v;
      }
#pragma unroll
      for (int msk = 1; msk < 16; msk <<= 1) {
        s += __shfl_xor(s, msk);
        sq += __shfl_xor(sq, msk);
      }
      if (l16 == 0) {
        int rl = tm * 16 + quad * 4 + r;
        red[w][rl][0] = s;
        red[w][rl][1] = sq;
      }
    }
  __syncthreads();
  if (tid < 64) {
    float s = red[0][tid][0] + red[1][tid][0] + red[2][tid][0] + red[3][tid][0];
    float sq = red[0][tid][1] + red[1][tid][1] + red[2][tid][1] + red[3][tid][1];
    float mu = s * (1.f / 256.f);
    float var = sq * (1.f / 256.f) - mu * mu;
    stats[tid][0] = mu;
    stats[tid][1] = rsqrtf(var + 1e-5f);
  }
  __syncthreads();
#pragma unroll
  for (int tm = 0; tm < 4; ++tm)
#pragma unroll
    for (int r = 0; r < 4; ++r) {
      int rl = tm * 16 + quad * 4 + r;
      float mu = stats[rl][0], rstd = stats[rl][1];
#pragma unroll
      for (int tn = 0; tn < 4; ++tn) {
        int col = w * 64 + tn * 16 + l16;
        out[(size_t)(m0 + rl) * COUT + col] = (acc[tm][tn][r] - mu) * rstd * g[tn] + be[tn];
      }
    }
}

// ---------------------------------------------------------------------------
extern "C" void kernel_launch(void* const* d_in, const int* in_sizes, int n_in,
                              void* d_out, int out_size, void* d_ws, size_t ws_size,
                              hipStream_t stream) {
  const float* xyz_hi    = (const float*)d_in[0];
  const float* xyz_lo    = (const float*)d_in[1];
  const float* feat_skip = (const float*)d_in[2];
  const float* feat_lo   = (const float*)d_in[3];
  const float* W1        = (const float*)d_in[4];
  const float* b1        = (const float*)d_in[5];
  const float* W2        = (const float*)d_in[6];
  const float* b2        = (const float*)d_in[7];
  const float* gamma     = (const float*)d_in[8];
  const float* beta      = (const float*)d_in[9];
  float* out = (float*)d_out;

  char* ws = (char*)d_ws;
  u16*   W1aT  = (u16*)(ws + 16777216);          // 131072
  u16*   W1bT  = (u16*)(ws + 16908288);          // 262144
  u16*   W2T   = (u16*)(ws + 17170432);          // 131072
  float* wq_g  = (float*)(ws + 17301504);        // 393216
  int*   iq_g  = (int*)(ws + 17694720);          // 393216
  float* G     = (float*)(ws + 18087936);        // 8388608

  knn_wconv_kernel<<<640, 512, 0, stream>>>(xyz_hi, xyz_lo, W1, W2,
                                            wq_g, iq_g, W1aT, W1bT, W2T);
  ggemm_kernel<<<(BB * SS) / 32, 256, 0, stream>>>(feat_lo, W1bT, G);
  gemm12_kernel<<<MTOT / 64, 256, 0, stream>>>(feat_skip, W1aT, b1, G, wq_g, iq_g,
                                               W2T, b2, gamma, beta, out);
}

// Round 11
// 182.271 us; speedup vs baseline: 1.1403x; 1.0199x over previous
//
#include <hip/hip_runtime.h>
#include <hip/hip_bf16.h>
#include <stdint.h>

typedef unsigned short u16;
typedef __attribute__((ext_vector_type(8))) short short8;
typedef __attribute__((ext_vector_type(4))) float f32x4;

#define BB 4
#define NN 8192
#define SS 2048
#define MTOT 32768
#define CSKIP 256
#define CLO 512
#define CIN 768
#define COUT 256

__device__ __forceinline__ u16 f2bf(float f) {
  unsigned u = __float_as_uint(f);
  u += 0x7fffu + ((u >> 16) & 1u);
  return (u16)(u >> 16);
}

__device__ __forceinline__ void gl_lds16(const void* g, void* l) {
  __builtin_amdgcn_global_load_lds(
      (const __attribute__((address_space(1))) void*)g,
      (__attribute__((address_space(3))) void*)l, 16, 0, 0);
}

// ---------------------------------------------------------------------------
// K0: uniform prep — weights -> bf16 transposed (W1aT/W1bT/W2T) + pack
// xyz_lo into float4 array sxyz_g (for scalar-load knn).
// ---------------------------------------------------------------------------
__global__ __launch_bounds__(256) void wconv_kernel(const float* __restrict__ W1,
                                                    const float* __restrict__ W2,
                                                    const float* __restrict__ xyz_lo,
                                                    u16* __restrict__ W1aT,
                                                    u16* __restrict__ W1bT,
                                                    u16* __restrict__ W2T,
                                                    float4* __restrict__ sxyz_g) {
  int i = blockIdx.x * 256 + threadIdx.x;
  if (i < 65536) {                       // W1aT: n=i>>8, k=i&255
    int n = i >> 8, k = i & 255;
    W1aT[i] = f2bf(W1[(size_t)k * COUT + n]);
  } else if (i < 196608) {               // W1bT: n=j>>9, k=j&511
    int j = i - 65536;
    int n = j >> 9, k = j & 511;
    W1bT[j] = f2bf(W1[(size_t)(256 + k) * COUT + n]);
  } else if (i < 262144) {               // W2T
    int j = i - 196608;
    int n = j >> 8, k = j & 255;
    W2T[j] = f2bf(W2[(size_t)k * COUT + n]);
  } else if (i < 262144 + BB * SS) {     // pack xyz_lo -> float4
    int j = i - 262144;
    sxyz_g[j] = make_float4(xyz_lo[j * 3 + 0], xyz_lo[j * 3 + 1],
                            xyz_lo[j * 3 + 2], 0.f);
  }
}

// ---------------------------------------------------------------------------
// K1: KNN (K=3). lane = query, wave = 256-candidate partition. Candidates are
// wave-uniform -> scalar s_load_dwordx4 from packed sxyz_g (readfirstlane
// forces uniformity); no LDS staging, no ds_read pipe cost. Branchless
// min/med3 insert (R10's branch is always taken wave-wide — reverted).
// Diff-form fp32 distances (expansion form flips near-ties — R3 failure).
// ---------------------------------------------------------------------------
__global__ __launch_bounds__(512) void knn_kernel(
    const float* __restrict__ xyz_hi, const float4* __restrict__ sxyz_g,
    float* __restrict__ wq_g, int* __restrict__ iq_g) {
  __shared__ float md[8][64][3];
  __shared__ int   mi[8][64][3];

  int tid = threadIdx.x;
  int blk = blockIdx.x;
  int b = blk >> 7;
  int wave = tid >> 6, lane = tid & 63;
  int qm = blk * 64 + lane;
  float qx = xyz_hi[(size_t)qm * 3 + 0];
  float qy = xyz_hi[(size_t)qm * 3 + 1];
  float qz = xyz_hi[(size_t)qm * 3 + 2];

  const float4* cand = sxyz_g + b * SS;
  int j0 = __builtin_amdgcn_readfirstlane(wave * 256);

  float b0 = 1e30f, b1 = 1e30f, b2 = 1e30f;
  int i0 = -1, i1 = -1, i2 = -1;
#pragma unroll 8
  for (int jj = 0; jj < 256; ++jj) {
    int j = j0 + jj;
    float4 p = cand[j];                  // uniform -> s_load_dwordx4
    float dx = p.x - qx, dy = p.y - qy, dz = p.z - qz;
    float d = fmaf(dx, dx, fmaf(dy, dy, dz * dz));
    bool c0 = d < b0, c1 = d < b1, c2 = d < b2;
    float nb0 = fminf(b0, d);
    float nb1 = __builtin_amdgcn_fmed3f(b0, b1, d);
    float nb2 = __builtin_amdgcn_fmed3f(b1, b2, d);
    int ni0 = c0 ? j : i0;
    int ni1 = c0 ? i0 : (c1 ? j : i1);
    int ni2 = c1 ? i1 : (c2 ? j : i2);
    b0 = nb0; b1 = nb1; b2 = nb2;
    i0 = ni0; i1 = ni1; i2 = ni2;
  }
  md[wave][lane][0] = b0; mi[wave][lane][0] = i0;
  md[wave][lane][1] = b1; mi[wave][lane][1] = i1;
  md[wave][lane][2] = b2; mi[wave][lane][2] = i2;
  __syncthreads();

  if (tid < 64) {
    int q = tid;
    float fb0 = 1e30f, fb1 = 1e30f, fb2 = 1e30f;
    int fi0 = -1, fi1 = -1, fi2 = -1;
    for (int p = 0; p < 8; ++p)
#pragma unroll
      for (int s = 0; s < 3; ++s) {
        float d = md[p][q][s]; int ix = mi[p][q][s];
        if (d < fb2 || (d == fb2 && ix < fi2)) {
          fb2 = d; fi2 = ix;
          if (fb2 < fb1 || (fb2 == fb1 && fi2 < fi1)) {
            float t = fb1; fb1 = fb2; fb2 = t; int ti = fi1; fi1 = fi2; fi2 = ti;
          }
          if (fb1 < fb0 || (fb1 == fb0 && fi1 < fi0)) {
            float t = fb0; fb0 = fb1; fb1 = t; int ti = fi0; fi0 = fi1; fi1 = ti;
          }
        }
      }
    int qm2 = blk * 64 + q;
    float d0 = sqrtf(fb0), d1 = sqrtf(fb1), d2 = sqrtf(fb2);
    float inv0 = 1.0f / (d0 + 1e-8f);
    float inv1 = 1.0f / (d1 + 1e-8f);
    float inv2 = 1.0f / (d2 + 1e-8f);
    float s = inv0 + inv1 + inv2;
    wq_g[(size_t)qm2 * 3 + 0] = inv0 / s;
    wq_g[(size_t)qm2 * 3 + 1] = inv1 / s;
    wq_g[(size_t)qm2 * 3 + 2] = inv2 / s;
    iq_g[(size_t)qm2 * 3 + 0] = fi0;
    iq_g[(size_t)qm2 * 3 + 1] = fi1;
    iq_g[(size_t)qm2 * 3 + 2] = fi2;
  }
}

// ---------------------------------------------------------------------------
// K2: ggemm — G = feat_lo @ W1b  (dense, M=8192, K=512, N=256, fp32 out).
// Tile 32x256, 256 thr, BK=32, grid 256.
// ---------------------------------------------------------------------------
__global__ __launch_bounds__(256, 4) void ggemm_kernel(
    const float* __restrict__ feat_lo, const u16* __restrict__ W1bT,
    float* __restrict__ G) {
  __shared__ u16 As[32 * 40];
  __shared__ u16 Bs[256 * 32];
  int tid = threadIdx.x;
  int m0 = blockIdx.x << 5;
  int w = tid >> 6, lane = tid & 63;
  int quad = lane >> 4, l16 = lane & 15;

  int srow = tid >> 3, s4 = (tid & 7) << 2;
  const float* arow = feat_lo + (size_t)(m0 + srow) * CLO + s4;
  u16* As_dst = As + srow * 40 + s4;

  f32x4 zero = {0.f, 0.f, 0.f, 0.f};
  f32x4 acc[2][4];
#pragma unroll
  for (int tm = 0; tm < 2; ++tm)
#pragma unroll
    for (int tn = 0; tn < 4; ++tn) acc[tm][tn] = zero;

  for (int kc = 0; kc < 16; ++kc) {
    __syncthreads();
#pragma unroll
    for (int r = 0; r < 4; ++r) {
      int u = tid + r * 256;
      int nrow = u >> 2, c = u & 3;
      int cg = c ^ (nrow & 3);
      gl_lds16(W1bT + (size_t)nrow * CLO + kc * 32 + cg * 8, (char*)Bs + u * 16);
    }
    float4 av = *(const float4*)(arow + kc * 32);
    union { __hip_bfloat162 h2[2]; uint2 u2; } pk;
    pk.h2[0] = __float22bfloat162_rn(make_float2(av.x, av.y));
    pk.h2[1] = __float22bfloat162_rn(make_float2(av.z, av.w));
    *(uint2*)As_dst = pk.u2;
    __syncthreads();

    short8 af[2], bf[4];
#pragma unroll
    for (int t = 0; t < 2; ++t)
      af[t] = *(const short8*)(As + (t * 16 + l16) * 40 + quad * 8);
#pragma unroll
    for (int t = 0; t < 4; ++t) {
      int rr = w * 64 + t * 16 + l16;
      bf[t] = *(const short8*)(Bs + (rr * 4 + (quad ^ (rr & 3))) * 8);
    }
#pragma unroll
    for (int tm = 0; tm < 2; ++tm)
#pragma unroll
      for (int tn = 0; tn < 4; ++tn)
        acc[tm][tn] = __builtin_amdgcn_mfma_f32_16x16x32_bf16(af[tm], bf[tn], acc[tm][tn], 0, 0, 0);
  }

#pragma unroll
  for (int tm = 0; tm < 2; ++tm)
#pragma unroll
    for (int tn = 0; tn < 4; ++tn) {
      int col = w * 64 + tn * 16 + l16;
#pragma unroll
      for (int r = 0; r < 4; ++r) {
        int row = m0 + tm * 16 + quad * 4 + r;
        G[(size_t)row * COUT + col] = acc[tm][tn][r];
      }
    }
}

// ---------------------------------------------------------------------------
// K3: fused MLP — phase 1: Htile = relu(skip@W1a + b1 + IDW-gather(G)) -> LDS
// (bf16, rows padded to 264); phase 2: out = LN(Htile@W2 + b2).
// Tile 64x256, 256 thr, grid 512.
// ---------------------------------------------------------------------------
__global__ __launch_bounds__(256, 2) void gemm12_kernel(
    const float* __restrict__ feat_skip, const u16* __restrict__ W1aT,
    const float* __restrict__ b1, const float* __restrict__ G,
    const float* __restrict__ wq_g, const int* __restrict__ iq_g,
    const u16* __restrict__ W2T, const float* __restrict__ b2,
    const float* __restrict__ gamma, const float* __restrict__ beta,
    float* __restrict__ out) {
  __shared__ u16 Hs[64 * 264];
  __shared__ u16 Bs[256 * 32];
  __shared__ u16 As[64 * 40];
  __shared__ float swq[192];
  __shared__ int   siq[192];
  __shared__ float red[4][64][2];
  __shared__ float stats[64][2];
  int tid = threadIdx.x;
  int m0 = blockIdx.x << 6;
  int bS = (m0 >> 13) * SS;
  int w = tid >> 6, lane = tid & 63;
  int quad = lane >> 4, l16 = lane & 15;

  if (tid < 192) {
    swq[tid] = wq_g[(size_t)m0 * 3 + tid];
    siq[tid] = iq_g[(size_t)m0 * 3 + tid];
  }

  int srow = tid >> 2, sc8 = (tid & 3) << 3;
  const float* arow = feat_skip + (size_t)(m0 + srow) * CSKIP + sc8;
  u16* As_dst = As + srow * 40 + sc8;

  f32x4 zero = {0.f, 0.f, 0.f, 0.f};
  f32x4 acc[4][4];
#pragma unroll
  for (int tm = 0; tm < 4; ++tm)
#pragma unroll
    for (int tn = 0; tn < 4; ++tn) acc[tm][tn] = zero;

  // ---- phase 1: skip @ W1a ----
  for (int kc = 0; kc < 8; ++kc) {
    __syncthreads();
#pragma unroll
    for (int r = 0; r < 4; ++r) {
      int u = tid + r * 256;
      int nrow = u >> 2, c = u & 3;
      int cg = c ^ (nrow & 3);
      gl_lds16(W1aT + (size_t)nrow * CSKIP + kc * 32 + cg * 8, (char*)Bs + u * 16);
    }
    float4 x0 = *(const float4*)(arow + kc * 32);
    float4 x1 = *(const float4*)(arow + kc * 32 + 4);
    union { __hip_bfloat162 h2[4]; uint4 u4; } pk;
    pk.h2[0] = __float22bfloat162_rn(make_float2(x0.x, x0.y));
    pk.h2[1] = __float22bfloat162_rn(make_float2(x0.z, x0.w));
    pk.h2[2] = __float22bfloat162_rn(make_float2(x1.x, x1.y));
    pk.h2[3] = __float22bfloat162_rn(make_float2(x1.z, x1.w));
    *(uint4*)As_dst = pk.u4;
    __syncthreads();

    short8 af[4], bf[4];
#pragma unroll
    for (int t = 0; t < 4; ++t)
      af[t] = *(const short8*)(As + (t * 16 + l16) * 40 + quad * 8);
#pragma unroll
    for (int t = 0; t < 4; ++t) {
      int rr = w * 64 + t * 16 + l16;
      bf[t] = *(const short8*)(Bs + (rr * 4 + (quad ^ (rr & 3))) * 8);
    }
#pragma unroll
    for (int tm = 0; tm < 4; ++tm)
#pragma unroll
      for (int tn = 0; tn < 4; ++tn)
        acc[tm][tn] = __builtin_amdgcn_mfma_f32_16x16x32_bf16(af[tm], bf[tn], acc[tm][tn], 0, 0, 0);
  }

  // ---- phase 1 epilogue: bias + IDW gather + relu -> Hs ----
  {
    float bias[4];
#pragma unroll
    for (int tn = 0; tn < 4; ++tn) bias[tn] = b1[w * 64 + tn * 16 + l16];
#pragma unroll
    for (int tm = 0; tm < 4; ++tm)
#pragma unroll
      for (int r = 0; r < 4; ++r) {
        int rl = tm * 16 + quad * 4 + r;
        float w0 = swq[rl * 3 + 0], w1 = swq[rl * 3 + 1], w2 = swq[rl * 3 + 2];
        const float* g0 = G + (size_t)(bS + siq[rl * 3 + 0]) * COUT;
        const float* g1 = G + (size_t)(bS + siq[rl * 3 + 1]) * COUT;
        const float* g2 = G + (size_t)(bS + siq[rl * 3 + 2]) * COUT;
#pragma unroll
        for (int tn = 0; tn < 4; ++tn) {
          int col = w * 64 + tn * 16 + l16;
          float gv = fmaf(w0, g0[col], fmaf(w1, g1[col], w2 * g2[col]));
          float v = acc[tm][tn][r] + bias[tn] + gv;
          v = v > 0.f ? v : 0.f;
          Hs[rl * 264 + col] = f2bf(v);
        }
      }
  }

  // ---- phase 2: Hs @ W2 + LN ----
#pragma unroll
  for (int tm = 0; tm < 4; ++tm)
#pragma unroll
    for (int tn = 0; tn < 4; ++tn) acc[tm][tn] = zero;

  for (int kc = 0; kc < 8; ++kc) {
    __syncthreads();
#pragma unroll
    for (int r = 0; r < 4; ++r) {
      int u = tid + r * 256;
      int nrow = u >> 2, c = u & 3;
      int cg = c ^ (nrow & 3);
      gl_lds16(W2T + (size_t)nrow * COUT + kc * 32 + cg * 8, (char*)Bs + u * 16);
    }
    __syncthreads();

    short8 af[4], bf[4];
#pragma unroll
    for (int t = 0; t < 4; ++t)
      af[t] = *(const short8*)(Hs + (t * 16 + l16) * 264 + kc * 32 + quad * 8);
#pragma unroll
    for (int t = 0; t < 4; ++t) {
      int rr = w * 64 + t * 16 + l16;
      bf[t] = *(const short8*)(Bs + (rr * 4 + (quad ^ (rr & 3))) * 8);
    }
#pragma unroll
    for (int tm = 0; tm < 4; ++tm)
#pragma unroll
      for (int tn = 0; tn < 4; ++tn)
        acc[tm][tn] = __builtin_amdgcn_mfma_f32_16x16x32_bf16(af[tm], bf[tn], acc[tm][tn], 0, 0, 0);
  }

  float bias[4], g[4], be[4];
#pragma unroll
  for (int tn = 0; tn < 4; ++tn) {
    int col = w * 64 + tn * 16 + l16;
    bias[tn] = b2[col]; g[tn] = gamma[col]; be[tn] = beta[col];
  }
#pragma unroll
  for (int tm = 0; tm < 4; ++tm)
#pragma unroll
    for (int r = 0; r < 4; ++r) {
      float s = 0.f, sq = 0.f;
#pragma unroll
      for (int tn = 0; tn < 4; ++tn) {
        float v = acc[tm][tn][r] + bias[tn];
        acc[tm][tn][r] = v;
        s += v; sq += v * v;
      }
#pragma unroll
      for (int msk = 1; msk < 16; msk <<= 1) {
        s += __shfl_xor(s, msk);
        sq += __shfl_xor(sq, msk);
      }
      if (l16 == 0) {
        int rl = tm * 16 + quad * 4 + r;
        red[w][rl][0] = s;
        red[w][rl][1] = sq;
      }
    }
  __syncthreads();
  if (tid < 64) {
    float s = red[0][tid][0] + red[1][tid][0] + red[2][tid][0] + red[3][tid][0];
    float sq = red[0][tid][1] + red[1][tid][1] + red[2][tid][1] + red[3][tid][1];
    float mu = s * (1.f / 256.f);
    float var = sq * (1.f / 256.f) - mu * mu;
    stats[tid][0] = mu;
    stats[tid][1] = rsqrtf(var + 1e-5f);
  }
  __syncthreads();
#pragma unroll
  for (int tm = 0; tm < 4; ++tm)
#pragma unroll
    for (int r = 0; r < 4; ++r) {
      int rl = tm * 16 + quad * 4 + r;
      float mu = stats[rl][0], rstd = stats[rl][1];
#pragma unroll
      for (int tn = 0; tn < 4; ++tn) {
        int col = w * 64 + tn * 16 + l16;
        out[(size_t)(m0 + rl) * COUT + col] = (acc[tm][tn][r] - mu) * rstd * g[tn] + be[tn];
      }
    }
}

// ---------------------------------------------------------------------------
extern "C" void kernel_launch(void* const* d_in, const int* in_sizes, int n_in,
                              void* d_out, int out_size, void* d_ws, size_t ws_size,
                              hipStream_t stream) {
  const float* xyz_hi    = (const float*)d_in[0];
  const float* xyz_lo    = (const float*)d_in[1];
  const float* feat_skip = (const float*)d_in[2];
  const float* feat_lo   = (const float*)d_in[3];
  const float* W1        = (const float*)d_in[4];
  const float* b1        = (const float*)d_in[5];
  const float* W2        = (const float*)d_in[6];
  const float* b2        = (const float*)d_in[7];
  const float* gamma     = (const float*)d_in[8];
  const float* beta      = (const float*)d_in[9];
  float* out = (float*)d_out;

  char* ws = (char*)d_ws;
  u16*    W1aT   = (u16*)(ws + 16777216);          // 131072
  u16*    W1bT   = (u16*)(ws + 16908288);          // 262144
  u16*    W2T    = (u16*)(ws + 17170432);          // 131072
  float*  wq_g   = (float*)(ws + 17301504);        // 393216
  int*    iq_g   = (int*)(ws + 17694720);          // 393216
  float*  G      = (float*)(ws + 18087936);        // 8388608
  float4* sxyz_g = (float4*)(ws + 26476544);       // 131072

  wconv_kernel<<<1056, 256, 0, stream>>>(W1, W2, xyz_lo, W1aT, W1bT, W2T, sxyz_g);
  knn_kernel<<<MTOT / 64, 512, 0, stream>>>(xyz_hi, sxyz_g, wq_g, iq_g);
  ggemm_kernel<<<(BB * SS) / 32, 256, 0, stream>>>(feat_lo, W1bT, G);
  gemm12_kernel<<<MTOT / 64, 256, 0, stream>>>(feat_skip, W1aT, b1, G, wq_g, iq_g,
                                               W2T, b2, gamma, beta, out);
}

// Round 13
// 178.874 us; speedup vs baseline: 1.1620x; 1.0190x over previous
//
#include <hip/hip_runtime.h>
#include <hip/hip_bf16.h>
#include <stdint.h>

typedef unsigned short u16;
typedef __attribute__((ext_vector_type(8))) short short8;
typedef __attribute__((ext_vector_type(4))) float f32x4;

#define BB 4
#define NN 8192
#define SS 2048
#define MTOT 32768
#define CSKIP 256
#define CLO 512
#define CIN 768
#define COUT 256

__device__ __forceinline__ u16 f2bf(float f) {
  unsigned u = __float_as_uint(f);
  u += 0x7fffu + ((u >> 16) & 1u);
  return (u16)(u >> 16);
}

__device__ __forceinline__ void gl_lds16(const void* g, void* l) {
  __builtin_amdgcn_global_load_lds(
      (const __attribute__((address_space(1))) void*)g,
      (__attribute__((address_space(3))) void*)l, 16, 0, 0);
}

// ---------------------------------------------------------------------------
// K1: blocks 0..511 = KNN (K=3): 64 queries/block, 16 waves x 128 candidates,
// lane = query. Candidates wave-uniform -> scalar/broadcast loads straight
// from xyz_lo (no pack, no LDS staging). Branchless min/med3 insert,
// diff-form fp32 distances (expansion form flips near-ties — R3 failure).
// blocks 512..575 = weight conversion (W1aT/W1bT/W2T), independent of knn.
// ---------------------------------------------------------------------------
__global__ __launch_bounds__(1024) void knn_wconv_kernel(
    const float* __restrict__ xyz_hi, const float* __restrict__ xyz_lo,
    const float* __restrict__ W1, const float* __restrict__ W2,
    float* __restrict__ wq_g, int* __restrict__ iq_g,
    u16* __restrict__ W1aT, u16* __restrict__ W1bT, u16* __restrict__ W2T) {
  int blk = blockIdx.x;
  int tid = threadIdx.x;
  if (blk >= 512) {
    // ---- wconv: 262144 elems over 64 blocks x 1024 thr (4 iters) ----
    int base = (blk - 512) * 1024 + tid;
    for (int i = base; i < 262144; i += 65536) {
      if (i < 65536) {                       // W1aT: n=i>>8, k=i&255
        int n = i >> 8, k = i & 255;
        W1aT[i] = f2bf(W1[(size_t)k * COUT + n]);
      } else if (i < 196608) {               // W1bT: n=j>>9, k=j&511
        int j = i - 65536;
        int n = j >> 9, k = j & 511;
        W1bT[j] = f2bf(W1[(size_t)(256 + k) * COUT + n]);
      } else {                               // W2T
        int j = i - 196608;
        int n = j >> 8, k = j & 255;
        W2T[j] = f2bf(W2[(size_t)k * COUT + n]);
      }
    }
    return;
  }

  // ---- knn ----
  __shared__ float md[16][64][3];
  __shared__ int   mi[16][64][3];

  int b = blk >> 7;
  int wave = tid >> 6, lane = tid & 63;
  int qm = blk * 64 + lane;
  float qx = xyz_hi[(size_t)qm * 3 + 0];
  float qy = xyz_hi[(size_t)qm * 3 + 1];
  float qz = xyz_hi[(size_t)qm * 3 + 2];

  const float* xl = xyz_lo + (size_t)b * SS * 3;
  int j0 = __builtin_amdgcn_readfirstlane(wave * 128);

  float b0 = 1e30f, b1 = 1e30f, b2 = 1e30f;
  int i0 = -1, i1 = -1, i2 = -1;
#pragma unroll 8
  for (int jj = 0; jj < 128; ++jj) {
    int j = j0 + jj;
    float px = xl[3 * j + 0];            // uniform -> scalar load / broadcast
    float py = xl[3 * j + 1];
    float pz = xl[3 * j + 2];
    float dx = px - qx, dy = py - qy, dz = pz - qz;
    float d = fmaf(dx, dx, fmaf(dy, dy, dz * dz));
    bool c0 = d < b0, c1 = d < b1, c2 = d < b2;
    float nb0 = fminf(b0, d);
    float nb1 = __builtin_amdgcn_fmed3f(b0, b1, d);
    float nb2 = __builtin_amdgcn_fmed3f(b1, b2, d);
    int ni0 = c0 ? j : i0;
    int ni1 = c0 ? i0 : (c1 ? j : i1);
    int ni2 = c1 ? i1 : (c2 ? j : i2);
    b0 = nb0; b1 = nb1; b2 = nb2;
    i0 = ni0; i1 = ni1; i2 = ni2;
  }
  md[wave][lane][0] = b0; mi[wave][lane][0] = i0;
  md[wave][lane][1] = b1; mi[wave][lane][1] = i1;
  md[wave][lane][2] = b2; mi[wave][lane][2] = i2;
  __syncthreads();

  if (tid < 64) {
    int q = tid;
    float fb0 = 1e30f, fb1 = 1e30f, fb2 = 1e30f;
    int fi0 = -1, fi1 = -1, fi2 = -1;
    // parts are contiguous ascending ranges; merge with index tiebreak
    for (int p = 0; p < 16; ++p)
#pragma unroll
      for (int s = 0; s < 3; ++s) {
        float d = md[p][q][s]; int ix = mi[p][q][s];
        if (d < fb2 || (d == fb2 && ix < fi2)) {
          fb2 = d; fi2 = ix;
          if (fb2 < fb1 || (fb2 == fb1 && fi2 < fi1)) {
            float t = fb1; fb1 = fb2; fb2 = t; int ti = fi1; fi1 = fi2; fi2 = ti;
          }
          if (fb1 < fb0 || (fb1 == fb0 && fi1 < fi0)) {
            float t = fb0; fb0 = fb1; fb1 = t; int ti = fi0; fi0 = fi1; fi1 = ti;
          }
        }
      }
    int qm2 = blk * 64 + q;
    float d0 = sqrtf(fb0), d1 = sqrtf(fb1), d2 = sqrtf(fb2);
    float inv0 = 1.0f / (d0 + 1e-8f);
    float inv1 = 1.0f / (d1 + 1e-8f);
    float inv2 = 1.0f / (d2 + 1e-8f);
    float s = inv0 + inv1 + inv2;
    wq_g[(size_t)qm2 * 3 + 0] = inv0 / s;
    wq_g[(size_t)qm2 * 3 + 1] = inv1 / s;
    wq_g[(size_t)qm2 * 3 + 2] = inv2 / s;
    iq_g[(size_t)qm2 * 3 + 0] = fi0;
    iq_g[(size_t)qm2 * 3 + 1] = fi1;
    iq_g[(size_t)qm2 * 3 + 2] = fi2;
  }
}

// ---------------------------------------------------------------------------
// K2: ggemm — G = feat_lo @ W1b  (dense, M=8192, K=512, N=256, fp32 out).
// Tile 32x256, 256 thr, BK=32, grid 256.
// ---------------------------------------------------------------------------
__global__ __launch_bounds__(256, 4) void ggemm_kernel(
    const float* __restrict__ feat_lo, const u16* __restrict__ W1bT,
    float* __restrict__ G) {
  __shared__ u16 As[32 * 40];
  __shared__ u16 Bs[256 * 32];
  int tid = threadIdx.x;
  int m0 = blockIdx.x << 5;
  int w = tid >> 6, lane = tid & 63;
  int quad = lane >> 4, l16 = lane & 15;

  int srow = tid >> 3, s4 = (tid & 7) << 2;
  const float* arow = feat_lo + (size_t)(m0 + srow) * CLO + s4;
  u16* As_dst = As + srow * 40 + s4;

  f32x4 zero = {0.f, 0.f, 0.f, 0.f};
  f32x4 acc[2][4];
#pragma unroll
  for (int tm = 0; tm < 2; ++tm)
#pragma unroll
    for (int tn = 0; tn < 4; ++tn) acc[tm][tn] = zero;

  for (int kc = 0; kc < 16; ++kc) {
    __syncthreads();
#pragma unroll
    for (int r = 0; r < 4; ++r) {
      int u = tid + r * 256;
      int nrow = u >> 2, c = u & 3;
      int cg = c ^ (nrow & 3);
      gl_lds16(W1bT + (size_t)nrow * CLO + kc * 32 + cg * 8, (char*)Bs + u * 16);
    }
    float4 av = *(const float4*)(arow + kc * 32);
    union { __hip_bfloat162 h2[2]; uint2 u2; } pk;
    pk.h2[0] = __float22bfloat162_rn(make_float2(av.x, av.y));
    pk.h2[1] = __float22bfloat162_rn(make_float2(av.z, av.w));
    *(uint2*)As_dst = pk.u2;
    __syncthreads();

    short8 af[2], bf[4];
#pragma unroll
    for (int t = 0; t < 2; ++t)
      af[t] = *(const short8*)(As + (t * 16 + l16) * 40 + quad * 8);
#pragma unroll
    for (int t = 0; t < 4; ++t) {
      int rr = w * 64 + t * 16 + l16;
      bf[t] = *(const short8*)(Bs + (rr * 4 + (quad ^ (rr & 3))) * 8);
    }
#pragma unroll
    for (int tm = 0; tm < 2; ++tm)
#pragma unroll
      for (int tn = 0; tn < 4; ++tn)
        acc[tm][tn] = __builtin_amdgcn_mfma_f32_16x16x32_bf16(af[tm], bf[tn], acc[tm][tn], 0, 0, 0);
  }

#pragma unroll
  for (int tm = 0; tm < 2; ++tm)
#pragma unroll
    for (int tn = 0; tn < 4; ++tn) {
      int col = w * 64 + tn * 16 + l16;
#pragma unroll
      for (int r = 0; r < 4; ++r) {
        int row = m0 + tm * 16 + quad * 4 + r;
        G[(size_t)row * COUT + col] = acc[tm][tn][r];
      }
    }
}

// ---------------------------------------------------------------------------
// K3: fused MLP — phase 1: Htile = relu(skip@W1a + b1 + IDW-gather(G)) -> LDS
// (bf16, rows padded to 264); phase 2: out = LN(Htile@W2 + b2), with
// double-buffered B staging (A is LDS-resident Hs -> 1 barrier/iter).
// Tile 64x256, 256 thr, grid 512, ~74 KB LDS -> 2 blocks/CU.
// ---------------------------------------------------------------------------
__global__ __launch_bounds__(256, 2) void gemm12_kernel(
    const float* __restrict__ feat_skip, const u16* __restrict__ W1aT,
    const float* __restrict__ b1, const float* __restrict__ G,
    const float* __restrict__ wq_g, const int* __restrict__ iq_g,
    const u16* __restrict__ W2T, const float* __restrict__ b2,
    const float* __restrict__ gamma, const float* __restrict__ beta,
    float* __restrict__ out) {
  __shared__ u16 Hs[64 * 264];
  __shared__ u16 Bs[256 * 32];
  __shared__ u16 Bs2[256 * 32];
  __shared__ u16 As[64 * 40];
  __shared__ float swq[192];
  __shared__ int   siq[192];
  __shared__ float red[4][64][2];
  __shared__ float stats[64][2];
  int tid = threadIdx.x;
  int m0 = blockIdx.x << 6;
  int bS = (m0 >> 13) * SS;
  int w = tid >> 6, lane = tid & 63;
  int quad = lane >> 4, l16 = lane & 15;

  if (tid < 192) {
    swq[tid] = wq_g[(size_t)m0 * 3 + tid];
    siq[tid] = iq_g[(size_t)m0 * 3 + tid];
  }

  int srow = tid >> 2, sc8 = (tid & 3) << 3;
  const float* arow = feat_skip + (size_t)(m0 + srow) * CSKIP + sc8;
  u16* As_dst = As + srow * 40 + sc8;

  f32x4 zero = {0.f, 0.f, 0.f, 0.f};
  f32x4 acc[4][4];
#pragma unroll
  for (int tm = 0; tm < 4; ++tm)
#pragma unroll
    for (int tn = 0; tn < 4; ++tn) acc[tm][tn] = zero;

  // ---- phase 1: skip @ W1a (two-barrier; As single-buffered) ----
  for (int kc = 0; kc < 8; ++kc) {
    __syncthreads();
#pragma unroll
    for (int r = 0; r < 4; ++r) {
      int u = tid + r * 256;
      int nrow = u >> 2, c = u & 3;
      int cg = c ^ (nrow & 3);
      gl_lds16(W1aT + (size_t)nrow * CSKIP + kc * 32 + cg * 8, (char*)Bs + u * 16);
    }
    float4 x0 = *(const float4*)(arow + kc * 32);
    float4 x1 = *(const float4*)(arow + kc * 32 + 4);
    union { __hip_bfloat162 h2[4]; uint4 u4; } pk;
    pk.h2[0] = __float22bfloat162_rn(make_float2(x0.x, x0.y));
    pk.h2[1] = __float22bfloat162_rn(make_float2(x0.z, x0.w));
    pk.h2[2] = __float22bfloat162_rn(make_float2(x1.x, x1.y));
    pk.h2[3] = __float22bfloat162_rn(make_float2(x1.z, x1.w));
    *(uint4*)As_dst = pk.u4;
    __syncthreads();

    short8 af[4], bf[4];
#pragma unroll
    for (int t = 0; t < 4; ++t)
      af[t] = *(const short8*)(As + (t * 16 + l16) * 40 + quad * 8);
#pragma unroll
    for (int t = 0; t < 4; ++t) {
      int rr = w * 64 + t * 16 + l16;
      bf[t] = *(const short8*)(Bs + (rr * 4 + (quad ^ (rr & 3))) * 8);
    }
#pragma unroll
    for (int tm = 0; tm < 4; ++tm)
#pragma unroll
      for (int tn = 0; tn < 4; ++tn)
        acc[tm][tn] = __builtin_amdgcn_mfma_f32_16x16x32_bf16(af[tm], bf[tn], acc[tm][tn], 0, 0, 0);
  }

  // ---- phase 1 epilogue: bias + IDW gather + relu -> Hs ----
  {
    float bias[4];
#pragma unroll
    for (int tn = 0; tn < 4; ++tn) bias[tn] = b1[w * 64 + tn * 16 + l16];
#pragma unroll
    for (int tm = 0; tm < 4; ++tm)
#pragma unroll
      for (int r = 0; r < 4; ++r) {
        int rl = tm * 16 + quad * 4 + r;
        float w0 = swq[rl * 3 + 0], w1 = swq[rl * 3 + 1], w2 = swq[rl * 3 + 2];
        const float* g0 = G + (size_t)(bS + siq[rl * 3 + 0]) * COUT;
        const float* g1 = G + (size_t)(bS + siq[rl * 3 + 1]) * COUT;
        const float* g2 = G + (size_t)(bS + siq[rl * 3 + 2]) * COUT;
#pragma unroll
        for (int tn = 0; tn < 4; ++tn) {
          int col = w * 64 + tn * 16 + l16;
          float gv = fmaf(w0, g0[col], fmaf(w1, g1[col], w2 * g2[col]));
          float v = acc[tm][tn][r] + bias[tn] + gv;
          v = v > 0.f ? v : 0.f;
          Hs[rl * 264 + col] = f2bf(v);
        }
      }
  }

  // ---- phase 2: Hs @ W2 + LN, double-buffered B, 1 barrier/iter ----
#pragma unroll
  for (int tm = 0; tm < 4; ++tm)
#pragma unroll
    for (int tn = 0; tn < 4; ++tn) acc[tm][tn] = zero;

  __syncthreads();               // Hs writes visible; phase-1 Bs reads done
#pragma unroll
  for (int r = 0; r < 4; ++r) {  // stage kc=0 into Bs
    int u = tid + r * 256;
    int nrow = u >> 2, c = u & 3;
    int cg = c ^ (nrow & 3);
    gl_lds16(W2T + (size_t)nrow * COUT + cg * 8, (char*)Bs + u * 16);
  }
  for (int kc = 0; kc < 8; ++kc) {
    __syncthreads();             // B(kc) staged (vmcnt drained at barrier)
    u16* cur = (kc & 1) ? Bs2 : Bs;
    u16* nxt = (kc & 1) ? Bs : Bs2;
    if (kc + 1 < 8) {
#pragma unroll
      for (int r = 0; r < 4; ++r) {
        int u = tid + r * 256;
        int nrow = u >> 2, c = u & 3;
        int cg = c ^ (nrow & 3);
        gl_lds16(W2T + (size_t)nrow * COUT + (kc + 1) * 32 + cg * 8,
                 (char*)nxt + u * 16);
      }
    }
    short8 af[4], bf[4];
#pragma unroll
    for (int t = 0; t < 4; ++t)
      af[t] = *(const short8*)(Hs + (t * 16 + l16) * 264 + kc * 32 + quad * 8);
#pragma unroll
    for (int t = 0; t < 4; ++t) {
      int rr = w * 64 + t * 16 + l16;
      bf[t] = *(const short8*)(cur + (rr * 4 + (quad ^ (rr & 3))) * 8);
    }
#pragma unroll
    for (int tm = 0; tm < 4; ++tm)
#pragma unroll
      for (int tn = 0; tn < 4; ++tn)
        acc[tm][tn] = __builtin_amdgcn_mfma_f32_16x16x32_bf16(af[tm], bf[tn], acc[tm][tn], 0, 0, 0);
  }

  float bias[4], g[4], be[4];
#pragma unroll
  for (int tn = 0; tn < 4; ++tn) {
    int col = w * 64 + tn * 16 + l16;
    bias[tn] = b2[col]; g[tn] = gamma[col]; be[tn] = beta[col];
  }
#pragma unroll
  for (int tm = 0; tm < 4; ++tm)
#pragma unroll
    for (int r = 0; r < 4; ++r) {
      float s = 0.f, sq = 0.f;
#pragma unroll
      for (int tn = 0; tn < 4; ++tn) {
        float v = acc[tm][tn][r] + bias[tn];
        acc[tm][tn][r] = v;
        s += v; sq += v * v;
      }
#pragma unroll
      for (int msk = 1; msk < 16; msk <<= 1) {
        s += __shfl_xor(s, msk);
        sq += __shfl_xor(sq, msk);
      }
      if (l16 == 0) {
        int rl = tm * 16 + quad * 4 + r;
        red[w][rl][0] = s;
        red[w][rl][1] = sq;
      }
    }
  __syncthreads();
  if (tid < 64) {
    float s = red[0][tid][0] + red[1][tid][0] + red[2][tid][0] + red[3][tid][0];
    float sq = red[0][tid][1] + red[1][tid][1] + red[2][tid][1] + red[3][tid][1];
    float mu = s * (1.f / 256.f);
    float var = sq * (1.f / 256.f) - mu * mu;
    stats[tid][0] = mu;
    stats[tid][1] = rsqrtf(var + 1e-5f);
  }
  __syncthreads();
#pragma unroll
  for (int tm = 0; tm < 4; ++tm)
#pragma unroll
    for (int r = 0; r < 4; ++r) {
      int rl = tm * 16 + quad * 4 + r;
      float mu = stats[rl][0], rstd = stats[rl][1];
#pragma unroll
      for (int tn = 0; tn < 4; ++tn) {
        int col = w * 64 + tn * 16 + l16;
        out[(size_t)(m0 + rl) * COUT + col] = (acc[tm][tn][r] - mu) * rstd * g[tn] + be[tn];
      }
    }
}

// ---------------------------------------------------------------------------
extern "C" void kernel_launch(void* const* d_in, const int* in_sizes, int n_in,
                              void* d_out, int out_size, void* d_ws, size_t ws_size,
                              hipStream_t stream) {
  const float* xyz_hi    = (const float*)d_in[0];
  const float* xyz_lo    = (const float*)d_in[1];
  const float* feat_skip = (const float*)d_in[2];
  const float* feat_lo   = (const float*)d_in[3];
  const float* W1        = (const float*)d_in[4];
  const float* b1        = (const float*)d_in[5];
  const float* W2        = (const float*)d_in[6];
  const float* b2        = (const float*)d_in[7];
  const float* gamma     = (const float*)d_in[8];
  const float* beta      = (const float*)d_in[9];
  float* out = (float*)d_out;

  char* ws = (char*)d_ws;
  u16*   W1aT  = (u16*)(ws + 16777216);          // 131072
  u16*   W1bT  = (u16*)(ws + 16908288);          // 262144
  u16*   W2T   = (u16*)(ws + 17170432);          // 131072
  float* wq_g  = (float*)(ws + 17301504);        // 393216
  int*   iq_g  = (int*)(ws + 17694720);          // 393216
  float* G     = (float*)(ws + 18087936);        // 8388608

  knn_wconv_kernel<<<576, 1024, 0, stream>>>(xyz_hi, xyz_lo, W1, W2,
                                             wq_g, iq_g, W1aT, W1bT, W2T);
  ggemm_kernel<<<(BB * SS) / 32, 256, 0, stream>>>(feat_lo, W1bT, G);
  gemm12_kernel<<<MTOT / 64, 256, 0, stream>>>(feat_skip, W1aT, b1, G, wq_g, iq_g,
                                               W2T, b2, gamma, beta, out);
}